// Round 17
// baseline (136.060 us; speedup 1.0000x reference)
//
#include <hip/hip_runtime.h>
#include <cstdint>
#include <cstddef>

typedef _Float16 half8  __attribute__((ext_vector_type(8)));
typedef _Float16 half4v __attribute__((ext_vector_type(4)));
typedef float    f32x4  __attribute__((ext_vector_type(4)));

__device__ __forceinline__ f32x4 fzero4() {
  f32x4 v; v[0] = v[1] = v[2] = v[3] = 0.0f; return v;
}

__device__ __forceinline__ void gload16(const void* g, void* l) {
  __builtin_amdgcn_global_load_lds(
      (const __attribute__((address_space(1))) unsigned int*)g,
      (__attribute__((address_space(3))) unsigned int*)l, 16, 0, 0);
}

#define MFMA(a, b, c) __builtin_amdgcn_mfma_f32_16x16x32_f16(a, b, c, 0, 0, 0)
#define EXP2(x) __builtin_amdgcn_exp2f(x)

// 16-lane-row butterfly sum on the VALU pipe via DPP row_ror.
__device__ __forceinline__ float row16_sum(float x) {
#define STEP_(N)                                                         \
  {                                                                      \
    int t_ = __builtin_amdgcn_update_dpp(0, __float_as_int(x), 0x120 | N, \
                                         0xf, 0xf, true);                \
    x = x + __int_as_float(t_);                                          \
  }
  STEP_(8) STEP_(4) STEP_(2) STEP_(1)
#undef STEP_
  return x;
}

// ------------------------------------------- prep: weights cvt + mask bits
struct PrepArgs {
  const float* wsrc[4];
  _Float16*    wdst[4];
  const int*   mask;
  unsigned long long* mbits;
};

__global__ __launch_bounds__(256) void prep_kernel(PrepArgs a) {
  const int z = blockIdx.y;
  const int nthr = gridDim.x * blockDim.x;  // 131072
  const int t0 = blockIdx.x * blockDim.x + threadIdx.x;
  if (z < 4) {
    const float4* __restrict__ s = (const float4*)a.wsrc[z];
    half4v* __restrict__ d = (half4v*)a.wdst[z];
    float4 v[2];
#pragma unroll
    for (int k = 0; k < 2; ++k) v[k] = s[t0 + k * nthr];
#pragma unroll
    for (int k = 0; k < 2; ++k) {
      half4v h;
      h[0] = (_Float16)v[k].x; h[1] = (_Float16)v[k].y;
      h[2] = (_Float16)v[k].z; h[3] = (_Float16)v[k].w;
      d[t0 + k * nthr] = h;
    }
  } else {
    const int* __restrict__ src = a.mask;
    const unsigned char* __restrict__ s8 = (const unsigned char*)src;
    unsigned long long* __restrict__ dst = a.mbits;
    const int lane = threadIdx.x & 63;
    unsigned probe = 0;
#pragma unroll
    for (int e = 0; e < 16; ++e) probe |= s8[4 * (lane * 16 + e) + 1];
    const bool isbool = __any(probe != 0);

    const int gw = blockIdx.x * 4 + (threadIdx.x >> 6);  // 0..2047
    for (int ii = 0; ii < 32; ii += 8) {
      int mv[8];
#pragma unroll
      for (int k = 0; k < 8; ++k) {
        const int word = gw * 32 + ii + k;  // 0..65535
        const int t = word & 1023;
        const int kw = (word >> 10) & 15;
        const int b = word >> 14;
        const size_t idx = ((size_t)(b * 1024 + t)) * 1024 + kw * 64 + lane;
        mv[k] = isbool ? (int)s8[idx] : src[idx];
      }
#pragma unroll
      for (int k = 0; k < 8; ++k) {
        unsigned long long bal = __ballot(mv[k] != 0);
        if (lane == 0) dst[gw * 32 + ii + k] = bal;
      }
    }
  }
}

// ---------------------------------------------------------------- projections
// m97-structure: 128x128 tile, BK=64, SINGLE-buffered (32 KB -> 3 blocks/CU),
// 2 barriers/K-step; cross-block wave overlap (m114) hides the full drain.
// A-side: fused fp32->fp16 cvt via reg-staging; LOADA(kt+1) issued before the
// compute barrier so A-loads fly during COMP(kt). B-side: gload_lds + swizzle.
#define SM_SCALE 0.18033688011112042f /* 0.125 * log2(e) */

__global__ __launch_bounds__(256) void proj_kernel(
    const float* __restrict__ query, const float* __restrict__ key,
    const float* __restrict__ value, const _Float16* __restrict__ w16,
    const float* __restrict__ bq, const float* __restrict__ bk,
    const float* __restrict__ bv,
    const float* __restrict__ qg, const float* __restrict__ qbt,
    const float* __restrict__ kg, const float* __restrict__ kbt,
    _Float16* __restrict__ Qln, _Float16* __restrict__ Kln,
    _Float16* __restrict__ VT) {
  __shared__ _Float16 As[128 * 64];
  __shared__ _Float16 Bs[128 * 64];

  const int tid = threadIdx.x;
  const int w = tid >> 6, lane = tid & 63, g = lane >> 4, l15 = lane & 15;
  // XCD-aware bijective swizzle (nwg=768 -> q=96)
  const int flat = blockIdx.x;
  const int swz = (flat & 7) * 96 + (flat >> 3);
  const int bn = swz & 7;
  const int bm = (swz >> 3) & 31;
  const int z = swz >> 8;

  const float* Af = (z == 0) ? query : ((z == 1) ? key : value);
  const _Float16* W = w16 + (size_t)z * (1024 * 1024);
  const float* bias = (z == 0) ? bq : ((z == 1) ? bk : bv);

  const int wr = w >> 1, wc = w & 1;
  const int srow = (w << 3) + (lane >> 3);
  const int csw = ((lane & 7) ^ (lane >> 3)) << 3;  // W swizzled source col
  const int rsw = (l15 & 7) << 3;                   // read-side XOR

  // A reg-staging geometry: slot s -> row = s*32 + (tid>>3), colgrp = tid&7
  const int arow0 = tid >> 3;
  const int acg = tid & 7;
  const int axor = ((acg ^ (arow0 & 7)) << 3);

  f32x4 acc[4][4];
#pragma unroll
  for (int i = 0; i < 4; ++i)
#pragma unroll
    for (int j = 0; j < 4; ++j) acc[i][j] = fzero4();

  float4 va[4][2];

#define PROJ_LOADA(KT)                                                      \
  _Pragma("unroll") for (int s_ = 0; s_ < 4; ++s_) {                        \
    const float4* ap_ = (const float4*)(Af +                                \
        (size_t)(bm * 128 + s_ * 32 + arow0) * 1024 + (KT)*64 + acg * 8);   \
    va[s_][0] = ap_[0];                                                     \
    va[s_][1] = ap_[1];                                                     \
  }

#define PROJ_WRITEA()                                                       \
  _Pragma("unroll") for (int s_ = 0; s_ < 4; ++s_) {                        \
    half8 h_;                                                               \
    h_[0] = (_Float16)va[s_][0].x; h_[1] = (_Float16)va[s_][0].y;           \
    h_[2] = (_Float16)va[s_][0].z; h_[3] = (_Float16)va[s_][0].w;           \
    h_[4] = (_Float16)va[s_][1].x; h_[5] = (_Float16)va[s_][1].y;           \
    h_[6] = (_Float16)va[s_][1].z; h_[7] = (_Float16)va[s_][1].w;           \
    *(half8*)&As[(s_ * 32 + arow0) * 64 + axor] = h_;                       \
  }

#define PROJ_STAGEB(KT)                                                     \
  _Pragma("unroll") for (int r = 0; r < 4; ++r) {                           \
    gload16(W + (size_t)(bn * 128 + r * 32 + srow) * 1024 + (KT)*64 + csw,  \
            &Bs[(r * 32 + (w << 3)) * 64]);                                 \
  }

#define PROJ_COMP()                                                         \
  _Pragma("unroll") for (int kk = 0; kk < 2; ++kk) {                        \
    half8 a[4], b[4];                                                       \
    _Pragma("unroll") for (int mi = 0; mi < 4; ++mi) a[mi] =                \
        *(const half8*)&As[(wr * 64 + mi * 16 + l15) * 64 +                 \
                           ((kk * 32 + g * 8) ^ rsw)];                      \
    _Pragma("unroll") for (int nj = 0; nj < 4; ++nj) b[nj] =                \
        *(const half8*)&Bs[(wc * 64 + nj * 16 + l15) * 64 +                 \
                           ((kk * 32 + g * 8) ^ rsw)];                      \
    __builtin_amdgcn_s_setprio(1);                                          \
    _Pragma("unroll") for (int mi = 0; mi < 4; ++mi)                        \
        _Pragma("unroll") for (int nj = 0; nj < 4; ++nj) acc[mi][nj] =      \
            MFMA(a[mi], b[nj], acc[mi][nj]);                                \
    __builtin_amdgcn_s_setprio(0);                                          \
  }

  PROJ_LOADA(0)
  for (int kt = 0; kt < 16; ++kt) {
    PROJ_STAGEB(kt)
    asm volatile("s_waitcnt vmcnt(0)" ::: "memory");  // A-regs + B landed
    PROJ_WRITEA()
    if (kt < 15) PROJ_LOADA(kt + 1)  // fly during COMP(kt)
    __syncthreads();                 // lgkm drained -> As/Bs visible
    PROJ_COMP()
    __syncthreads();                 // all waves done reading before restage
  }
#undef PROJ_COMP
#undef PROJ_STAGEB
#undef PROJ_WRITEA
#undef PROJ_LOADA

  const int colbase = bn * 128 + wc * 64;
  const int h = colbase >> 6;
  const int rowbase = bm * 128 + wr * 64;

  float biasv[4];
#pragma unroll
  for (int nj = 0; nj < 4; ++nj) biasv[nj] = bias[colbase + nj * 16 + l15];

  if (z < 2) {
    const float* gamma = (z == 0) ? qg : kg;
    const float* beta = (z == 0) ? qbt : kbt;
    const float sc = (z == 0) ? SM_SCALE : 1.0f;  // fold softmax scale into Q
    _Float16* dst = (z == 0) ? Qln : Kln;
    float gam[4], bet[4];
#pragma unroll
    for (int nj = 0; nj < 4; ++nj) {
      gam[nj] = gamma[nj * 16 + l15] * sc;
      bet[nj] = beta[nj * 16 + l15] * sc;
    }
#pragma unroll
    for (int mi = 0; mi < 4; ++mi) {
#pragma unroll
      for (int j = 0; j < 4; ++j) {
        float vals[4], s = 0.f, s2 = 0.f;
#pragma unroll
        for (int nj = 0; nj < 4; ++nj) {
          float v = acc[mi][nj][j] + biasv[nj];
          vals[nj] = v; s += v; s2 += v * v;
        }
        s = row16_sum(s);
        s2 = row16_sum(s2);
        const float mu = s * (1.0f / 64.0f);
        const float var = s2 * (1.0f / 64.0f) - mu * mu;
        const float rs = rsqrtf(var + 1e-5f);
        const int r = rowbase + mi * 16 + g * 4 + j;
        const int b = r >> 10, t = r & 1023;
        _Float16* drow = dst + ((size_t)((b * 16 + h) * 1024 + t)) * 64;
#pragma unroll
        for (int nj = 0; nj < 4; ++nj)
          drow[nj * 16 + l15] =
              (_Float16)((vals[nj] - mu) * rs * gam[nj] + bet[nj]);
      }
    }
  } else {
#pragma unroll
    for (int mi = 0; mi < 4; ++mi) {
      const int r0 = rowbase + mi * 16 + g * 4;
      const int b = r0 >> 10, t0 = r0 & 1023;
#pragma unroll
      for (int nj = 0; nj < 4; ++nj) {
        const int dk = nj * 16 + l15;
        half4v pk;
#pragma unroll
        for (int j = 0; j < 4; ++j)
          pk[j] = (_Float16)(acc[mi][nj][j] + biasv[nj]);
        *(half4v*)&VT[((size_t)((b * 16 + h) * 64 + dk)) * 1024 + t0] = pk;
      }
    }
  }
}

// ---------------------------------------------------------------- attention
// Grid (bh=64 on x, qt=8 on y): qt-blocks of one head share an XCD L2.
#define PSTR 76

__global__ __launch_bounds__(512) void attn_kernel(
    const _Float16* __restrict__ Qln, const _Float16* __restrict__ Kln,
    const _Float16* __restrict__ VT,
    const unsigned long long* __restrict__ mbits, _Float16* __restrict__ X) {
  __shared__ _Float16 PQ[128 * PSTR];
  __shared__ _Float16 Ks[2][64 * 64];
  __shared__ _Float16 Vs[2][64 * 64];
  __shared__ unsigned long long Mb[2][128];

  const int tid = threadIdx.x;
  const int w = tid >> 6, lane = tid & 63, g = lane >> 4, l15 = lane & 15;
  const int qt = blockIdx.y;  // 0..7
  const int bh = blockIdx.x;  // 0..63
  const int b = bh >> 4, h = bh & 15;

  const int lr8 = lane >> 3;
  const int csw = ((lane & 7) ^ lr8) << 3;

  const _Float16* Qb = Qln + (size_t)bh * 65536;
  const _Float16* Kb = Kln + (size_t)bh * 65536;
  const _Float16* Vb = VT + (size_t)bh * 65536;
  const unsigned long long* mbb = mbits + (size_t)b * 16384 + qt * 128;

  gload16(Qb + (size_t)(qt * 128 + w * 16 + lr8) * 64 + csw, &PQ[(w * 16) * 64]);
  gload16(Qb + (size_t)(qt * 128 + w * 16 + 8 + lr8) * 64 + csw,
          &PQ[(w * 16 + 8) * 64]);
  gload16(Kb + (size_t)(w * 8 + lr8) * 64 + csw, &Ks[0][(w * 8) * 64]);
  gload16(Vb + (size_t)(w * 8 + lr8) * 1024 + csw, &Vs[0][(w * 8) * 64]);
  if (w == 0) gload16(mbb + lane * 2, &Mb[0][0]);
  asm volatile("s_waitcnt vmcnt(0)" ::: "memory");
  __syncthreads();

  const int rsw = (l15 & 7) << 3;
  half8 qf[2];
#pragma unroll
  for (int kk = 0; kk < 2; ++kk)
    qf[kk] = *(const half8*)&PQ[(w * 16 + l15) * 64 + ((kk * 32 + g * 8) ^ rsw)];
  asm volatile("s_waitcnt lgkmcnt(0)" ::: "memory");
  __syncthreads();

  f32x4 o[4];
  float lsum[4];
#pragma unroll
  for (int dn = 0; dn < 4; ++dn) o[dn] = fzero4();
#pragma unroll
  for (int j = 0; j < 4; ++j) lsum[j] = 0.f;

#define ATTN_TILE(KT, CUR, NXT, PF)                                          \
  {                                                                          \
    if (PF) {                                                                \
      gload16(Kb + (size_t)(((KT) + 1) * 64 + w * 8 + lr8) * 64 + csw,       \
              &Ks[NXT][(w * 8) * 64]);                                       \
      gload16(Vb + (size_t)(w * 8 + lr8) * 1024 + ((KT) + 1) * 64 + csw,     \
              &Vs[NXT][(w * 8) * 64]);                                       \
      if (w == 0)                                                            \
        gload16(mbb + (size_t)((KT) + 1) * 1024 + lane * 2, &Mb[NXT][0]);    \
    }                                                                        \
    f32x4 s[4];                                                              \
    _Pragma("unroll") for (int nj = 0; nj < 4; ++nj) s[nj] = fzero4();       \
    _Pragma("unroll") for (int kk = 0; kk < 2; ++kk) {                       \
      half8 qv = qf[kk];                                                     \
      __builtin_amdgcn_s_setprio(1);                                         \
      _Pragma("unroll") for (int nj = 0; nj < 4; ++nj) {                     \
        half8 kf = *(const half8*)&Ks[CUR][(nj * 16 + l15) * 64 +            \
                                          ((kk * 32 + g * 8) ^ rsw)];        \
        s[nj] = MFMA(qv, kf, s[nj]);                                         \
      }                                                                      \
      __builtin_amdgcn_s_setprio(0);                                         \
    }                                                                        \
    _Pragma("unroll") for (int j = 0; j < 4; ++j) {                          \
      const int lrow = w * 16 + g * 4 + j;                                   \
      const unsigned long long mw = Mb[CUR][lrow];                           \
      const unsigned lo = (unsigned)mw, hi = (unsigned)(mw >> 32);           \
      const float p0 = ((lo >> l15) & 1) ? 0.f : EXP2(s[0][j]);              \
      const float p1 = ((lo >> (l15 + 16)) & 1) ? 0.f : EXP2(s[1][j]);       \
      const float p2 = ((hi >> l15) & 1) ? 0.f : EXP2(s[2][j]);              \
      const float p3 = ((hi >> (l15 + 16)) & 1) ? 0.f : EXP2(s[3][j]);       \
      PQ[lrow * PSTR + 0 + l15] = (_Float16)p0;                              \
      PQ[lrow * PSTR + 16 + l15] = (_Float16)p1;                             \
      PQ[lrow * PSTR + 32 + l15] = (_Float16)p2;                             \
      PQ[lrow * PSTR + 48 + l15] = (_Float16)p3;                             \
      lsum[j] += (p0 + p1) + (p2 + p3);                                      \
    }                                                                        \
    _Pragma("unroll") for (int kk = 0; kk < 2; ++kk) {                       \
      half8 pa = *(const half8*)&PQ[(w * 16 + l15) * PSTR + kk * 32 + g * 8];\
      __builtin_amdgcn_s_setprio(1);                                         \
      _Pragma("unroll") for (int dn = 0; dn < 4; ++dn) {                     \
        half8 vf = *(const half8*)&Vs[CUR][(dn * 16 + l15) * 64 +            \
                                           ((kk * 32 + g * 8) ^ rsw)];       \
        o[dn] = MFMA(pa, vf, o[dn]);                                         \
      }                                                                      \
      __builtin_amdgcn_s_setprio(0);                                         \
    }                                                                        \
    if (PF) {                                                                \
      asm volatile("s_waitcnt vmcnt(0)" ::: "memory");                       \
      __syncthreads();                                                       \
    }                                                                        \
  }

  for (int kt = 0; kt < 16; kt += 2) {
    ATTN_TILE(kt, 0, 1, true);
    ATTN_TILE(kt + 1, 1, 0, (kt + 1) < 15);
  }
#undef ATTN_TILE

#pragma unroll
  for (int j = 0; j < 4; ++j) {
    const int t = qt * 128 + w * 16 + g * 4 + j;
    const float inv = 1.0f / row16_sum(lsum[j]);
    _Float16* xrow = X + ((size_t)(b * 1024 + t)) * 1024 + h * 64;
#pragma unroll
    for (int dn = 0; dn < 4; ++dn)
      xrow[dn * 16 + l15] = (_Float16)(o[dn][j] * inv);
  }
}

// ---------------------------------------------------------------- out proj
// 128x64 tiles (BK=64, 256 thr, 48 KB LDS): grid 512 -> 2 blocks/CU.
__global__ __launch_bounds__(256) void ogemm_kernel(
    const _Float16* __restrict__ Xin, const _Float16* __restrict__ Wo16,
    const float* __restrict__ bo, float* __restrict__ out) {
  __shared__ _Float16 As[2][128 * 64];
  __shared__ _Float16 Bs[2][64 * 64];

  const int tid = threadIdx.x;
  const int w = tid >> 6, lane = tid & 63, g = lane >> 4, l15 = lane & 15;
  const int flat = blockIdx.x;
  const int swz = (flat & 7) * 64 + (flat >> 3);  // XCD bijective (nwg=512)
  const int bn = swz & 15;   // 0..15 (64-col tiles)
  const int bm = swz >> 4;   // 0..31
  const int wr = w >> 1, wc = w & 1;
  const int srow = (w << 3) + (lane >> 3);
  const int lr8 = lane >> 3;
  const int csw = ((lane & 7) ^ lr8) << 3;
  const int rsw = (l15 & 7) << 3;

  f32x4 acc[4][2];
#pragma unroll
  for (int i = 0; i < 4; ++i)
#pragma unroll
    for (int j = 0; j < 2; ++j) acc[i][j] = fzero4();

#define OG_STAGE(KT, BUF)                                                   \
  {                                                                         \
    _Pragma("unroll") for (int r = 0; r < 4; ++r) {                         \
      gload16(Xin + (size_t)(bm * 128 + r * 32 + srow) * 1024 + (KT)*64 +   \
                  csw,                                                      \
              &As[BUF][(r * 32 + (w << 3)) * 64]);                          \
    }                                                                       \
    _Pragma("unroll") for (int c = 0; c < 2; ++c) {                         \
      gload16(Wo16 + (size_t)(bn * 64 + w * 16 + c * 8 + lr8) * 1024 +      \
                  (KT)*64 + csw,                                            \
              &Bs[BUF][(w * 16 + c * 8) * 64]);                             \
    }                                                                       \
  }

#define OG_TILE(KT, CUR, NXT, PF)                                           \
  {                                                                         \
    if (PF) { OG_STAGE((KT) + 1, NXT) }                                     \
    _Pragma("unroll") for (int kk = 0; kk < 2; ++kk) {                      \
      half8 a[4], b[2];                                                     \
      _Pragma("unroll") for (int mi = 0; mi < 4; ++mi) a[mi] =              \
          *(const half8*)&As[CUR][(wr * 64 + mi * 16 + l15) * 64 +          \
                                  ((kk * 32 + g * 8) ^ rsw)];               \
      _Pragma("unroll") for (int nj = 0; nj < 2; ++nj) b[nj] =              \
          *(const half8*)&Bs[CUR][(wc * 32 + nj * 16 + l15) * 64 +          \
                                  ((kk * 32 + g * 8) ^ rsw)];               \
      __builtin_amdgcn_s_setprio(1);                                        \
      _Pragma("unroll") for (int mi = 0; mi < 4; ++mi)                      \
          _Pragma("unroll") for (int nj = 0; nj < 2; ++nj) acc[mi][nj] =    \
              MFMA(a[mi], b[nj], acc[mi][nj]);                              \
      __builtin_amdgcn_s_setprio(0);                                        \
    }                                                                       \
    if (PF) {                                                               \
      asm volatile("s_waitcnt vmcnt(0)" ::: "memory");                      \
      __syncthreads();                                                      \
    }                                                                       \
  }

  OG_STAGE(0, 0)
  asm volatile("s_waitcnt vmcnt(0)" ::: "memory");
  __syncthreads();
  for (int kt = 0; kt < 16; kt += 2) {
    OG_TILE(kt, 0, 1, true);
    OG_TILE(kt + 1, 1, 0, (kt + 1) < 15);
  }
#undef OG_TILE
#undef OG_STAGE

  const int colbase = bn * 64 + wc * 32;
  const int rowbase = bm * 128 + wr * 64;
  float biasv[2];
#pragma unroll
  for (int nj = 0; nj < 2; ++nj) biasv[nj] = bo[colbase + nj * 16 + l15];
#pragma unroll
  for (int mi = 0; mi < 4; ++mi)
#pragma unroll
    for (int nj = 0; nj < 2; ++nj)
#pragma unroll
      for (int j = 0; j < 4; ++j) {
        const int r = rowbase + mi * 16 + g * 4 + j;
        out[(size_t)r * 1024 + colbase + nj * 16 + l15] =
            acc[mi][nj][j] + biasv[nj];
      }
}

// ---------------------------------------------------------------- launch
// Workspace layout (56.5 MB):
//   [0 .. 8MB)   X   [24..32MB) w16   [32..40MB) Qln
//   [40..48MB)   Kln [48..56MB) VTp   [56..56.5MB) mbits
extern "C" void kernel_launch(void* const* d_in, const int* in_sizes, int n_in,
                              void* d_out, int out_size, void* d_ws,
                              size_t ws_size, hipStream_t stream) {
  const float* query = (const float*)d_in[0];
  const float* key = (const float*)d_in[1];
  const float* value = (const float*)d_in[2];
  const int* mask = (const int*)d_in[3];
  const float* Wq = (const float*)d_in[4];
  const float* bq = (const float*)d_in[5];
  const float* Wk = (const float*)d_in[6];
  const float* bk = (const float*)d_in[7];
  const float* Wv = (const float*)d_in[8];
  const float* bv = (const float*)d_in[9];
  const float* Wo = (const float*)d_in[10];
  const float* bo = (const float*)d_in[11];
  const float* qg = (const float*)d_in[12];
  const float* qb = (const float*)d_in[13];
  const float* kg = (const float*)d_in[14];
  const float* kb = (const float*)d_in[15];
  float* out = (float*)d_out;

  const size_t M4 = (size_t)4 * 1024 * 1024;
  const size_t M1 = (size_t)1024 * 1024;
  _Float16* base = (_Float16*)d_ws;
  _Float16* X = base;                // [0..8MB)
  _Float16* w16 = base + 3 * M4;     // [24..32MB)
  _Float16* Qln = base + 4 * M4;     // [32..40MB)
  _Float16* Kln = base + 5 * M4;     // [40..48MB)
  _Float16* VTp = base + 6 * M4;     // [48..56MB)
  unsigned long long* mbits = (unsigned long long*)(base + 7 * M4);

  PrepArgs pa;
  pa.wsrc[0] = Wq; pa.wsrc[1] = Wk; pa.wsrc[2] = Wv; pa.wsrc[3] = Wo;
  pa.wdst[0] = w16; pa.wdst[1] = w16 + M1; pa.wdst[2] = w16 + 2 * M1;
  pa.wdst[3] = w16 + 3 * M1;
  pa.mask = mask;
  pa.mbits = mbits;

  prep_kernel<<<dim3(512, 5), 256, 0, stream>>>(pa);
  proj_kernel<<<dim3(768), 256, 0, stream>>>(
      query, key, value, w16, bq, bk, bv, qg, qb, kg, kb, Qln, Kln, VTp);
  attn_kernel<<<dim3(64, 8), 512, 0, stream>>>(Qln, Kln, VTp, mbits, X);
  ogemm_kernel<<<dim3(512), 256, 0, stream>>>(X, w16 + 3 * M1, bo, out);
}

// Round 18
// 116.155 us; speedup vs baseline: 1.1714x; 1.1714x over previous
//
#include <hip/hip_runtime.h>
#include <cstdint>
#include <cstddef>

typedef _Float16 half8  __attribute__((ext_vector_type(8)));
typedef _Float16 half4v __attribute__((ext_vector_type(4)));
typedef float    f32x4  __attribute__((ext_vector_type(4)));

__device__ __forceinline__ f32x4 fzero4() {
  f32x4 v; v[0] = v[1] = v[2] = v[3] = 0.0f; return v;
}

__device__ __forceinline__ void gload16(const void* g, void* l) {
  __builtin_amdgcn_global_load_lds(
      (const __attribute__((address_space(1))) unsigned int*)g,
      (__attribute__((address_space(3))) unsigned int*)l, 16, 0, 0);
}

#define MFMA(a, b, c) __builtin_amdgcn_mfma_f32_16x16x32_f16(a, b, c, 0, 0, 0)
#define EXP2(x) __builtin_amdgcn_exp2f(x)

// 16-lane-row butterfly sum on the VALU pipe via DPP row_ror.
__device__ __forceinline__ float row16_sum(float x) {
#define STEP_(N)                                                         \
  {                                                                      \
    int t_ = __builtin_amdgcn_update_dpp(0, __float_as_int(x), 0x120 | N, \
                                         0xf, 0xf, true);                \
    x = x + __int_as_float(t_);                                          \
  }
  STEP_(8) STEP_(4) STEP_(2) STEP_(1)
#undef STEP_
  return x;
}

// ------------------------------------------------- fused prep: cvt + maskbits
struct PrepArgs {
  const float* src[7];
  _Float16*    dst[7];
  const int*   mask;
  unsigned long long* mbits;
};

__global__ __launch_bounds__(256) void prep_kernel(PrepArgs a) {
  const int z = blockIdx.y;
  const int nthr = gridDim.x * blockDim.x;  // 131072
  const int t0 = blockIdx.x * blockDim.x + threadIdx.x;
  if (z < 3) {
    const float4* __restrict__ s = (const float4*)a.src[z];
    half4v* __restrict__ d = (half4v*)a.dst[z];
    float4 v[8];
#pragma unroll
    for (int k = 0; k < 8; ++k) v[k] = s[t0 + k * nthr];
#pragma unroll
    for (int k = 0; k < 8; ++k) {
      half4v h;
      h[0] = (_Float16)v[k].x; h[1] = (_Float16)v[k].y;
      h[2] = (_Float16)v[k].z; h[3] = (_Float16)v[k].w;
      d[t0 + k * nthr] = h;
    }
  } else if (z < 7) {
    const float4* __restrict__ s = (const float4*)a.src[z];
    half4v* __restrict__ d = (half4v*)a.dst[z];
    float4 v[2];
#pragma unroll
    for (int k = 0; k < 2; ++k) v[k] = s[t0 + k * nthr];
#pragma unroll
    for (int k = 0; k < 2; ++k) {
      half4v h;
      h[0] = (_Float16)v[k].x; h[1] = (_Float16)v[k].y;
      h[2] = (_Float16)v[k].z; h[3] = (_Float16)v[k].w;
      d[t0 + k * nthr] = h;
    }
  } else {
    const int* __restrict__ src = a.mask;
    const unsigned char* __restrict__ s8 = (const unsigned char*)src;
    unsigned long long* __restrict__ dst = a.mbits;
    const int lane = threadIdx.x & 63;
    unsigned probe = 0;
#pragma unroll
    for (int e = 0; e < 16; ++e) probe |= s8[4 * (lane * 16 + e) + 1];
    const bool isbool = __any(probe != 0);

    const int gw = blockIdx.x * 4 + (threadIdx.x >> 6);  // 0..2047
    for (int ii = 0; ii < 32; ii += 8) {
      int mv[8];
#pragma unroll
      for (int k = 0; k < 8; ++k) {
        const int word = gw * 32 + ii + k;  // 0..65535
        const int t = word & 1023;
        const int kw = (word >> 10) & 15;
        const int b = word >> 14;
        const size_t idx = ((size_t)(b * 1024 + t)) * 1024 + kw * 64 + lane;
        mv[k] = isbool ? (int)s8[idx] : src[idx];
      }
#pragma unroll
      for (int k = 0; k < 8; ++k) {
        unsigned long long bal = __ballot(mv[k] != 0);
        if (lane == 0) dst[gw * 32 + ii + k] = bal;
      }
    }
  }
}

// ---------------------------------------------------------------- projections
// m97-exact structure: 128x128 tile, BK=64, SINGLE-buffered (32 KB -> 3
// blocks/CU), fp16 inputs, all staging via gload_lds + both-sides swizzle,
// 2 barriers/K-step. Cross-block wave overlap (m114) hides the drain.
#define SM_SCALE 0.18033688011112042f /* 0.125 * log2(e) */

__global__ __launch_bounds__(256) void proj_kernel(
    const _Float16* __restrict__ q16, const _Float16* __restrict__ k16,
    const _Float16* __restrict__ v16, const _Float16* __restrict__ w16,
    const float* __restrict__ bq, const float* __restrict__ bk,
    const float* __restrict__ bv,
    const float* __restrict__ qg, const float* __restrict__ qbt,
    const float* __restrict__ kg, const float* __restrict__ kbt,
    _Float16* __restrict__ Qln, _Float16* __restrict__ Kln,
    _Float16* __restrict__ VT) {
  __shared__ _Float16 As[128 * 64];
  __shared__ _Float16 Bs[128 * 64];

  const int tid = threadIdx.x;
  const int w = tid >> 6, lane = tid & 63, g = lane >> 4, l15 = lane & 15;
  // XCD-aware bijective swizzle (nwg=768 -> q=96)
  const int flat = blockIdx.x;
  const int swz = (flat & 7) * 96 + (flat >> 3);
  const int bn = swz & 7;
  const int bm = (swz >> 3) & 31;
  const int z = swz >> 8;

  const _Float16* A = (z == 0) ? q16 : ((z == 1) ? k16 : v16);
  const _Float16* W = w16 + (size_t)z * (1024 * 1024);
  const float* bias = (z == 0) ? bq : ((z == 1) ? bk : bv);

  const int wr = w >> 1, wc = w & 1;
  const int srow = (w << 3) + (lane >> 3);
  const int csw = ((lane & 7) ^ (lane >> 3)) << 3;  // swizzled source col
  const int rsw = (l15 & 7) << 3;                   // read-side XOR

  f32x4 acc[4][4];
#pragma unroll
  for (int i = 0; i < 4; ++i)
#pragma unroll
    for (int j = 0; j < 4; ++j) acc[i][j] = fzero4();

#define PROJ_STAGE(KT)                                                      \
  _Pragma("unroll") for (int r = 0; r < 4; ++r) {                           \
    const int row = r * 32 + srow;                                          \
    gload16(A + (size_t)(bm * 128 + row) * 1024 + (KT)*64 + csw,            \
            &As[(r * 32 + (w << 3)) * 64]);                                 \
    gload16(W + (size_t)(bn * 128 + row) * 1024 + (KT)*64 + csw,            \
            &Bs[(r * 32 + (w << 3)) * 64]);                                 \
  }

#define PROJ_COMP()                                                         \
  _Pragma("unroll") for (int kk = 0; kk < 2; ++kk) {                        \
    half8 a[4], b[4];                                                       \
    _Pragma("unroll") for (int mi = 0; mi < 4; ++mi) a[mi] =                \
        *(const half8*)&As[(wr * 64 + mi * 16 + l15) * 64 +                 \
                           ((kk * 32 + g * 8) ^ rsw)];                      \
    _Pragma("unroll") for (int nj = 0; nj < 4; ++nj) b[nj] =                \
        *(const half8*)&Bs[(wc * 64 + nj * 16 + l15) * 64 +                 \
                           ((kk * 32 + g * 8) ^ rsw)];                      \
    __builtin_amdgcn_s_setprio(1);                                          \
    _Pragma("unroll") for (int mi = 0; mi < 4; ++mi)                        \
        _Pragma("unroll") for (int nj = 0; nj < 4; ++nj) acc[mi][nj] =      \
            MFMA(a[mi], b[nj], acc[mi][nj]);                                \
    __builtin_amdgcn_s_setprio(0);                                          \
  }

  for (int kt = 0; kt < 16; ++kt) {
    PROJ_STAGE(kt)
    asm volatile("s_waitcnt vmcnt(0)" ::: "memory");
    __syncthreads();
    PROJ_COMP()
    __syncthreads();
  }
#undef PROJ_COMP
#undef PROJ_STAGE

  const int colbase = bn * 128 + wc * 64;
  const int h = colbase >> 6;
  const int rowbase = bm * 128 + wr * 64;

  float biasv[4];
#pragma unroll
  for (int nj = 0; nj < 4; ++nj) biasv[nj] = bias[colbase + nj * 16 + l15];

  if (z < 2) {
    const float* gamma = (z == 0) ? qg : kg;
    const float* beta = (z == 0) ? qbt : kbt;
    const float sc = (z == 0) ? SM_SCALE : 1.0f;  // fold softmax scale into Q
    _Float16* dst = (z == 0) ? Qln : Kln;
    float gam[4], bet[4];
#pragma unroll
    for (int nj = 0; nj < 4; ++nj) {
      gam[nj] = gamma[nj * 16 + l15] * sc;
      bet[nj] = beta[nj * 16 + l15] * sc;
    }
#pragma unroll
    for (int mi = 0; mi < 4; ++mi) {
#pragma unroll
      for (int j = 0; j < 4; ++j) {
        float vals[4], s = 0.f, s2 = 0.f;
#pragma unroll
        for (int nj = 0; nj < 4; ++nj) {
          float v = acc[mi][nj][j] + biasv[nj];
          vals[nj] = v; s += v; s2 += v * v;
        }
        s = row16_sum(s);
        s2 = row16_sum(s2);
        const float mu = s * (1.0f / 64.0f);
        const float var = s2 * (1.0f / 64.0f) - mu * mu;
        const float rs = rsqrtf(var + 1e-5f);
        const int r = rowbase + mi * 16 + g * 4 + j;
        const int b = r >> 10, t = r & 1023;
        _Float16* drow = dst + ((size_t)((b * 16 + h) * 1024 + t)) * 64;
#pragma unroll
        for (int nj = 0; nj < 4; ++nj)
          drow[nj * 16 + l15] =
              (_Float16)((vals[nj] - mu) * rs * gam[nj] + bet[nj]);
      }
    }
  } else {
#pragma unroll
    for (int mi = 0; mi < 4; ++mi) {
      const int r0 = rowbase + mi * 16 + g * 4;
      const int b = r0 >> 10, t0 = r0 & 1023;
#pragma unroll
      for (int nj = 0; nj < 4; ++nj) {
        const int dk = nj * 16 + l15;
        half4v pk;
#pragma unroll
        for (int j = 0; j < 4; ++j)
          pk[j] = (_Float16)(acc[mi][nj][j] + biasv[nj]);
        *(half4v*)&VT[((size_t)((b * 16 + h) * 64 + dk)) * 1024 + t0] = pk;
      }
    }
  }
}

// ---------------------------------------------------------------- attention
// Grid (bh=64 on x, qt=8 on y): qt-blocks of one head share an XCD L2.
#define PSTR 76

__global__ __launch_bounds__(512) void attn_kernel(
    const _Float16* __restrict__ Qln, const _Float16* __restrict__ Kln,
    const _Float16* __restrict__ VT,
    const unsigned long long* __restrict__ mbits, _Float16* __restrict__ X) {
  __shared__ _Float16 PQ[128 * PSTR];
  __shared__ _Float16 Ks[2][64 * 64];
  __shared__ _Float16 Vs[2][64 * 64];
  __shared__ unsigned long long Mb[2][128];

  const int tid = threadIdx.x;
  const int w = tid >> 6, lane = tid & 63, g = lane >> 4, l15 = lane & 15;
  const int qt = blockIdx.y;  // 0..7
  const int bh = blockIdx.x;  // 0..63
  const int b = bh >> 4, h = bh & 15;

  const int lr8 = lane >> 3;
  const int csw = ((lane & 7) ^ lr8) << 3;

  const _Float16* Qb = Qln + (size_t)bh * 65536;
  const _Float16* Kb = Kln + (size_t)bh * 65536;
  const _Float16* Vb = VT + (size_t)bh * 65536;
  const unsigned long long* mbb = mbits + (size_t)b * 16384 + qt * 128;

  gload16(Qb + (size_t)(qt * 128 + w * 16 + lr8) * 64 + csw, &PQ[(w * 16) * 64]);
  gload16(Qb + (size_t)(qt * 128 + w * 16 + 8 + lr8) * 64 + csw,
          &PQ[(w * 16 + 8) * 64]);
  gload16(Kb + (size_t)(w * 8 + lr8) * 64 + csw, &Ks[0][(w * 8) * 64]);
  gload16(Vb + (size_t)(w * 8 + lr8) * 1024 + csw, &Vs[0][(w * 8) * 64]);
  if (w == 0) gload16(mbb + lane * 2, &Mb[0][0]);
  asm volatile("s_waitcnt vmcnt(0)" ::: "memory");
  __syncthreads();

  const int rsw = (l15 & 7) << 3;
  half8 qf[2];
#pragma unroll
  for (int kk = 0; kk < 2; ++kk)
    qf[kk] = *(const half8*)&PQ[(w * 16 + l15) * 64 + ((kk * 32 + g * 8) ^ rsw)];
  asm volatile("s_waitcnt lgkmcnt(0)" ::: "memory");
  __syncthreads();

  f32x4 o[4];
  float lsum[4];
#pragma unroll
  for (int dn = 0; dn < 4; ++dn) o[dn] = fzero4();
#pragma unroll
  for (int j = 0; j < 4; ++j) lsum[j] = 0.f;

#define ATTN_TILE(KT, CUR, NXT, PF)                                          \
  {                                                                          \
    if (PF) {                                                                \
      gload16(Kb + (size_t)(((KT) + 1) * 64 + w * 8 + lr8) * 64 + csw,       \
              &Ks[NXT][(w * 8) * 64]);                                       \
      gload16(Vb + (size_t)(w * 8 + lr8) * 1024 + ((KT) + 1) * 64 + csw,     \
              &Vs[NXT][(w * 8) * 64]);                                       \
      if (w == 0)                                                            \
        gload16(mbb + (size_t)((KT) + 1) * 1024 + lane * 2, &Mb[NXT][0]);    \
    }                                                                        \
    f32x4 s[4];                                                              \
    _Pragma("unroll") for (int nj = 0; nj < 4; ++nj) s[nj] = fzero4();       \
    _Pragma("unroll") for (int kk = 0; kk < 2; ++kk) {                       \
      half8 qv = qf[kk];                                                     \
      __builtin_amdgcn_s_setprio(1);                                         \
      _Pragma("unroll") for (int nj = 0; nj < 4; ++nj) {                     \
        half8 kf = *(const half8*)&Ks[CUR][(nj * 16 + l15) * 64 +            \
                                          ((kk * 32 + g * 8) ^ rsw)];        \
        s[nj] = MFMA(qv, kf, s[nj]);                                         \
      }                                                                      \
      __builtin_amdgcn_s_setprio(0);                                         \
    }                                                                        \
    _Pragma("unroll") for (int j = 0; j < 4; ++j) {                          \
      const int lrow = w * 16 + g * 4 + j;                                   \
      const unsigned long long mw = Mb[CUR][lrow];                           \
      const unsigned lo = (unsigned)mw, hi = (unsigned)(mw >> 32);           \
      const float p0 = ((lo >> l15) & 1) ? 0.f : EXP2(s[0][j]);              \
      const float p1 = ((lo >> (l15 + 16)) & 1) ? 0.f : EXP2(s[1][j]);       \
      const float p2 = ((hi >> l15) & 1) ? 0.f : EXP2(s[2][j]);              \
      const float p3 = ((hi >> (l15 + 16)) & 1) ? 0.f : EXP2(s[3][j]);       \
      PQ[lrow * PSTR + 0 + l15] = (_Float16)p0;                              \
      PQ[lrow * PSTR + 16 + l15] = (_Float16)p1;                             \
      PQ[lrow * PSTR + 32 + l15] = (_Float16)p2;                             \
      PQ[lrow * PSTR + 48 + l15] = (_Float16)p3;                             \
      lsum[j] += (p0 + p1) + (p2 + p3);                                      \
    }                                                                        \
    _Pragma("unroll") for (int kk = 0; kk < 2; ++kk) {                       \
      half8 pa = *(const half8*)&PQ[(w * 16 + l15) * PSTR + kk * 32 + g * 8];\
      __builtin_amdgcn_s_setprio(1);                                         \
      _Pragma("unroll") for (int dn = 0; dn < 4; ++dn) {                     \
        half8 vf = *(const half8*)&Vs[CUR][(dn * 16 + l15) * 64 +            \
                                           ((kk * 32 + g * 8) ^ rsw)];       \
        o[dn] = MFMA(pa, vf, o[dn]);                                         \
      }                                                                      \
      __builtin_amdgcn_s_setprio(0);                                         \
    }                                                                        \
    if (PF) {                                                                \
      asm volatile("s_waitcnt vmcnt(0)" ::: "memory");                       \
      __syncthreads();                                                       \
    }                                                                        \
  }

  for (int kt = 0; kt < 16; kt += 2) {
    ATTN_TILE(kt, 0, 1, true);
    ATTN_TILE(kt + 1, 1, 0, (kt + 1) < 15);
  }
#undef ATTN_TILE

#pragma unroll
  for (int j = 0; j < 4; ++j) {
    const int t = qt * 128 + w * 16 + g * 4 + j;
    const float inv = 1.0f / row16_sum(lsum[j]);
    _Float16* xrow = X + ((size_t)(b * 1024 + t)) * 1024 + h * 64;
#pragma unroll
    for (int dn = 0; dn < 4; ++dn)
      xrow[dn * 16 + l15] = (_Float16)(o[dn][j] * inv);
  }
}

// ---------------------------------------------------------------- out proj
// 128x64 tiles (BK=64, 256 thr, 48 KB LDS dbuf): grid 512 -> 2 blocks/CU.
__global__ __launch_bounds__(256) void ogemm_kernel(
    const _Float16* __restrict__ Xin, const _Float16* __restrict__ Wo16,
    const float* __restrict__ bo, float* __restrict__ out) {
  __shared__ _Float16 As[2][128 * 64];
  __shared__ _Float16 Bs[2][64 * 64];

  const int tid = threadIdx.x;
  const int w = tid >> 6, lane = tid & 63, g = lane >> 4, l15 = lane & 15;
  const int flat = blockIdx.x;
  const int swz = (flat & 7) * 64 + (flat >> 3);  // XCD bijective (nwg=512)
  const int bn = swz & 15;   // 0..15 (64-col tiles)
  const int bm = swz >> 4;   // 0..31
  const int wr = w >> 1, wc = w & 1;
  const int srow = (w << 3) + (lane >> 3);
  const int lr8 = lane >> 3;
  const int csw = ((lane & 7) ^ lr8) << 3;
  const int rsw = (l15 & 7) << 3;

  f32x4 acc[4][2];
#pragma unroll
  for (int i = 0; i < 4; ++i)
#pragma unroll
    for (int j = 0; j < 2; ++j) acc[i][j] = fzero4();

#define OG_STAGE(KT, BUF)                                                   \
  {                                                                         \
    _Pragma("unroll") for (int r = 0; r < 4; ++r) {                         \
      gload16(Xin + (size_t)(bm * 128 + r * 32 + srow) * 1024 + (KT)*64 +   \
                  csw,                                                      \
              &As[BUF][(r * 32 + (w << 3)) * 64]);                          \
    }                                                                       \
    _Pragma("unroll") for (int c = 0; c < 2; ++c) {                         \
      gload16(Wo16 + (size_t)(bn * 64 + w * 16 + c * 8 + lr8) * 1024 +      \
                  (KT)*64 + csw,                                            \
              &Bs[BUF][(w * 16 + c * 8) * 64]);                             \
    }                                                                       \
  }

#define OG_TILE(KT, CUR, NXT, PF)                                           \
  {                                                                         \
    if (PF) { OG_STAGE((KT) + 1, NXT) }                                     \
    _Pragma("unroll") for (int kk = 0; kk < 2; ++kk) {                      \
      half8 a[4], b[2];                                                     \
      _Pragma("unroll") for (int mi = 0; mi < 4; ++mi) a[mi] =              \
          *(const half8*)&As[CUR][(wr * 64 + mi * 16 + l15) * 64 +          \
                                  ((kk * 32 + g * 8) ^ rsw)];               \
      _Pragma("unroll") for (int nj = 0; nj < 2; ++nj) b[nj] =              \
          *(const half8*)&Bs[CUR][(wc * 32 + nj * 16 + l15) * 64 +          \
                                  ((kk * 32 + g * 8) ^ rsw)];               \
      __builtin_amdgcn_s_setprio(1);                                        \
      _Pragma("unroll") for (int mi = 0; mi < 4; ++mi)                      \
          _Pragma("unroll") for (int nj = 0; nj < 2; ++nj) acc[mi][nj] =    \
              MFMA(a[mi], b[nj], acc[mi][nj]);                              \
      __builtin_amdgcn_s_setprio(0);                                        \
    }                                                                       \
    if (PF) {                                                               \
      asm volatile("s_waitcnt vmcnt(0)" ::: "memory");                      \
      __syncthreads();                                                      \
    }                                                                       \
  }

  OG_STAGE(0, 0)
  asm volatile("s_waitcnt vmcnt(0)" ::: "memory");
  __syncthreads();
  for (int kt = 0; kt < 16; kt += 2) {
    OG_TILE(kt, 0, 1, true);
    OG_TILE(kt + 1, 1, 0, (kt + 1) < 15);
  }
#undef OG_TILE
#undef OG_STAGE

  const int colbase = bn * 64 + wc * 32;
  const int rowbase = bm * 128 + wr * 64;
  float biasv[2];
#pragma unroll
  for (int nj = 0; nj < 2; ++nj) biasv[nj] = bo[colbase + nj * 16 + l15];
#pragma unroll
  for (int mi = 0; mi < 4; ++mi)
#pragma unroll
    for (int nj = 0; nj < 2; ++nj)
#pragma unroll
      for (int j = 0; j < 4; ++j) {
        const int r = rowbase + mi * 16 + g * 4 + j;
        out[(size_t)r * 1024 + colbase + nj * 16 + l15] =
            acc[mi][nj][j] + biasv[nj];
      }
}

// ---------------------------------------------------------------- launch
// Workspace layout (56.5 MB):
//   [0 .. 8MB)   q16 (phases 1-2), then X (phases 3-4; q16 dead)
//   [8 ..16MB)   k16   [16..24MB) v16   [24..32MB) w16
//   [32..40MB)   Qln   [40..48MB) Kln   [48..56MB) VTp
//   [56..56.5MB) mbits
extern "C" void kernel_launch(void* const* d_in, const int* in_sizes, int n_in,
                              void* d_out, int out_size, void* d_ws,
                              size_t ws_size, hipStream_t stream) {
  const float* query = (const float*)d_in[0];
  const float* key = (const float*)d_in[1];
  const float* value = (const float*)d_in[2];
  const int* mask = (const int*)d_in[3];
  const float* Wq = (const float*)d_in[4];
  const float* bq = (const float*)d_in[5];
  const float* Wk = (const float*)d_in[6];
  const float* bk = (const float*)d_in[7];
  const float* Wv = (const float*)d_in[8];
  const float* bv = (const float*)d_in[9];
  const float* Wo = (const float*)d_in[10];
  const float* bo = (const float*)d_in[11];
  const float* qg = (const float*)d_in[12];
  const float* qb = (const float*)d_in[13];
  const float* kg = (const float*)d_in[14];
  const float* kb = (const float*)d_in[15];
  float* out = (float*)d_out;

  const size_t M4 = (size_t)4 * 1024 * 1024;
  const size_t M1 = (size_t)1024 * 1024;
  _Float16* q16 = (_Float16*)d_ws;
  _Float16* k16 = q16 + M4;
  _Float16* v16 = k16 + M4;
  _Float16* w16 = v16 + M4;
  _Float16* Qln = w16 + M4;
  _Float16* Kln = Qln + M4;
  _Float16* VTp = Kln + M4;
  _Float16* X = q16;  // aliases q16 — dead after proj, written by attn
  unsigned long long* mbits = (unsigned long long*)(VTp + M4);  // 56..56.5MB

  PrepArgs pa;
  pa.src[0] = query; pa.src[1] = key; pa.src[2] = value;
  pa.src[3] = Wq; pa.src[4] = Wk; pa.src[5] = Wv; pa.src[6] = Wo;
  pa.dst[0] = q16; pa.dst[1] = k16; pa.dst[2] = v16;
  pa.dst[3] = w16; pa.dst[4] = w16 + M1; pa.dst[5] = w16 + 2 * M1;
  pa.dst[6] = w16 + 3 * M1;
  pa.mask = mask;
  pa.mbits = mbits;

  prep_kernel<<<dim3(512, 8), 256, 0, stream>>>(pa);
  proj_kernel<<<dim3(768), 256, 0, stream>>>(
      q16, k16, v16, w16, bq, bk, bv, qg, qb, kg, kb, Qln, Kln, VTp);
  attn_kernel<<<dim3(64, 8), 512, 0, stream>>>(Qln, Kln, VTp, mbits, X);
  ogemm_kernel<<<dim3(512), 256, 0, stream>>>(X, w16 + 3 * M1, bo, out);
}

// Round 19
// 115.398 us; speedup vs baseline: 1.1790x; 1.0066x over previous
//
#include <hip/hip_runtime.h>
#include <cstdint>
#include <cstddef>

typedef _Float16 half8  __attribute__((ext_vector_type(8)));
typedef _Float16 half4v __attribute__((ext_vector_type(4)));
typedef float    f32x4  __attribute__((ext_vector_type(4)));

__device__ __forceinline__ f32x4 fzero4() {
  f32x4 v; v[0] = v[1] = v[2] = v[3] = 0.0f; return v;
}

__device__ __forceinline__ void gload16(const void* g, void* l) {
  __builtin_amdgcn_global_load_lds(
      (const __attribute__((address_space(1))) unsigned int*)g,
      (__attribute__((address_space(3))) unsigned int*)l, 16, 0, 0);
}

#define MFMA(a, b, c) __builtin_amdgcn_mfma_f32_16x16x32_f16(a, b, c, 0, 0, 0)
#define EXP2(x) __builtin_amdgcn_exp2f(x)

// 16-lane-row butterfly sum on the VALU pipe via DPP row_ror.
__device__ __forceinline__ float row16_sum(float x) {
#define STEP_(N)                                                         \
  {                                                                      \
    int t_ = __builtin_amdgcn_update_dpp(0, __float_as_int(x), 0x120 | N, \
                                         0xf, 0xf, true);                \
    x = x + __int_as_float(t_);                                          \
  }
  STEP_(8) STEP_(4) STEP_(2) STEP_(1)
#undef STEP_
  return x;
}

// ------------------------------------------------- fused prep: cvt + maskbits
// mbits2 layout: [row=b*1024+t][kgrp(4)][c(4)] u64; bit l of (row,kg,c)
//   <-> mask[row][kg*256 + l*4 + c]. Produced by int4 loads + 4 ballots.
struct PrepArgs {
  const float* src[7];
  _Float16*    dst[7];
  const int*   mask;
  unsigned long long* mbits;
};

__global__ __launch_bounds__(256) void prep_kernel(PrepArgs a) {
  const int z = blockIdx.y;
  const int nthr = gridDim.x * blockDim.x;  // 131072
  const int t0 = blockIdx.x * blockDim.x + threadIdx.x;
  if (z < 3) {
    const float4* __restrict__ s = (const float4*)a.src[z];
    half4v* __restrict__ d = (half4v*)a.dst[z];
    float4 v[8];
#pragma unroll
    for (int k = 0; k < 8; ++k) v[k] = s[t0 + k * nthr];
#pragma unroll
    for (int k = 0; k < 8; ++k) {
      half4v h;
      h[0] = (_Float16)v[k].x; h[1] = (_Float16)v[k].y;
      h[2] = (_Float16)v[k].z; h[3] = (_Float16)v[k].w;
      d[t0 + k * nthr] = h;
    }
  } else if (z < 7) {
    const float4* __restrict__ s = (const float4*)a.src[z];
    half4v* __restrict__ d = (half4v*)a.dst[z];
    float4 v[2];
#pragma unroll
    for (int k = 0; k < 2; ++k) v[k] = s[t0 + k * nthr];
#pragma unroll
    for (int k = 0; k < 2; ++k) {
      half4v h;
      h[0] = (_Float16)v[k].x; h[1] = (_Float16)v[k].y;
      h[2] = (_Float16)v[k].z; h[3] = (_Float16)v[k].w;
      d[t0 + k * nthr] = h;
    }
  } else {
    const int* __restrict__ src = a.mask;
    const unsigned char* __restrict__ s8 = (const unsigned char*)src;
    unsigned long long* __restrict__ dst = a.mbits;
    const int lane = threadIdx.x & 63;
    unsigned probe = 0;
#pragma unroll
    for (int e = 0; e < 16; ++e) probe |= s8[4 * (lane * 16 + e) + 1];
    const bool isbool = __any(probe != 0);

    const int wv = blockIdx.x * 4 + (threadIdx.x >> 6);  // 0..2047
    if (!isbool) {
      const int4* __restrict__ s4 = (const int4*)src;
      int4 mv[8];
#pragma unroll
      for (int i = 0; i < 8; ++i) {
        const int unit = wv * 8 + i;  // 0..16383
        const int row = unit >> 2, kg = unit & 3;
        mv[i] = s4[row * 256 + kg * 64 + lane];
      }
#pragma unroll
      for (int i = 0; i < 8; ++i) {
        const int unit = wv * 8 + i;
        unsigned long long w0 = __ballot(mv[i].x != 0);
        unsigned long long w1 = __ballot(mv[i].y != 0);
        unsigned long long w2 = __ballot(mv[i].z != 0);
        unsigned long long w3 = __ballot(mv[i].w != 0);
        if (lane == 0) {
          unsigned long long* p = dst + (size_t)unit * 4;
          p[0] = w0; p[1] = w1; p[2] = w2; p[3] = w3;
        }
      }
    } else {
      // bool-byte encoding fallback (not taken for this harness)
      for (int i = 0; i < 8; ++i) {
        const int unit = wv * 8 + i;
        const int row = unit >> 2, kg = unit & 3;
#pragma unroll
        for (int c = 0; c < 4; ++c) {
          int m = s8[(size_t)row * 1024 + kg * 256 + lane * 4 + c];
          unsigned long long bw = __ballot(m != 0);
          if (lane == 0) dst[(size_t)unit * 4 + c] = bw;
        }
      }
    }
  }
}

// ---------------------------------------------------------------- projections
// m97-exact structure: 128x128 tile, BK=64, SINGLE-buffered (32 KB -> 3
// blocks/CU), fp16 inputs, all staging via gload_lds + both-sides swizzle,
// 2 barriers/K-step. Cross-block wave overlap (m114) hides the drain.
#define SM_SCALE 0.18033688011112042f /* 0.125 * log2(e) */

__global__ __launch_bounds__(256) void proj_kernel(
    const _Float16* __restrict__ q16, const _Float16* __restrict__ k16,
    const _Float16* __restrict__ v16, const _Float16* __restrict__ w16,
    const float* __restrict__ bq, const float* __restrict__ bk,
    const float* __restrict__ bv,
    const float* __restrict__ qg, const float* __restrict__ qbt,
    const float* __restrict__ kg, const float* __restrict__ kbt,
    _Float16* __restrict__ Qln, _Float16* __restrict__ Kln,
    _Float16* __restrict__ VT) {
  __shared__ _Float16 As[128 * 64];
  __shared__ _Float16 Bs[128 * 64];

  const int tid = threadIdx.x;
  const int w = tid >> 6, lane = tid & 63, g = lane >> 4, l15 = lane & 15;
  // XCD-aware bijective swizzle (nwg=768 -> q=96)
  const int flat = blockIdx.x;
  const int swz = (flat & 7) * 96 + (flat >> 3);
  const int bn = swz & 7;
  const int bm = (swz >> 3) & 31;
  const int z = swz >> 8;

  const _Float16* A = (z == 0) ? q16 : ((z == 1) ? k16 : v16);
  const _Float16* W = w16 + (size_t)z * (1024 * 1024);
  const float* bias = (z == 0) ? bq : ((z == 1) ? bk : bv);

  const int wr = w >> 1, wc = w & 1;
  const int srow = (w << 3) + (lane >> 3);
  const int csw = ((lane & 7) ^ (lane >> 3)) << 3;  // swizzled source col
  const int rsw = (l15 & 7) << 3;                   // read-side XOR

  f32x4 acc[4][4];
#pragma unroll
  for (int i = 0; i < 4; ++i)
#pragma unroll
    for (int j = 0; j < 4; ++j) acc[i][j] = fzero4();

#define PROJ_STAGE(KT)                                                      \
  _Pragma("unroll") for (int r = 0; r < 4; ++r) {                           \
    const int row = r * 32 + srow;                                          \
    gload16(A + (size_t)(bm * 128 + row) * 1024 + (KT)*64 + csw,            \
            &As[(r * 32 + (w << 3)) * 64]);                                 \
    gload16(W + (size_t)(bn * 128 + row) * 1024 + (KT)*64 + csw,            \
            &Bs[(r * 32 + (w << 3)) * 64]);                                 \
  }

#define PROJ_COMP()                                                         \
  _Pragma("unroll") for (int kk = 0; kk < 2; ++kk) {                        \
    half8 a[4], b[4];                                                       \
    _Pragma("unroll") for (int mi = 0; mi < 4; ++mi) a[mi] =                \
        *(const half8*)&As[(wr * 64 + mi * 16 + l15) * 64 +                 \
                           ((kk * 32 + g * 8) ^ rsw)];                      \
    _Pragma("unroll") for (int nj = 0; nj < 4; ++nj) b[nj] =                \
        *(const half8*)&Bs[(wc * 64 + nj * 16 + l15) * 64 +                 \
                           ((kk * 32 + g * 8) ^ rsw)];                      \
    __builtin_amdgcn_s_setprio(1);                                          \
    _Pragma("unroll") for (int mi = 0; mi < 4; ++mi)                        \
        _Pragma("unroll") for (int nj = 0; nj < 4; ++nj) acc[mi][nj] =      \
            MFMA(a[mi], b[nj], acc[mi][nj]);                                \
    __builtin_amdgcn_s_setprio(0);                                          \
  }

  for (int kt = 0; kt < 16; ++kt) {
    PROJ_STAGE(kt)
    asm volatile("s_waitcnt vmcnt(0)" ::: "memory");
    __syncthreads();
    PROJ_COMP()
    __syncthreads();
  }
#undef PROJ_COMP
#undef PROJ_STAGE

  const int colbase = bn * 128 + wc * 64;
  const int h = colbase >> 6;
  const int rowbase = bm * 128 + wr * 64;

  float biasv[4];
#pragma unroll
  for (int nj = 0; nj < 4; ++nj) biasv[nj] = bias[colbase + nj * 16 + l15];

  if (z < 2) {
    const float* gamma = (z == 0) ? qg : kg;
    const float* beta = (z == 0) ? qbt : kbt;
    const float sc = (z == 0) ? SM_SCALE : 1.0f;  // fold softmax scale into Q
    _Float16* dst = (z == 0) ? Qln : Kln;
    float gam[4], bet[4];
#pragma unroll
    for (int nj = 0; nj < 4; ++nj) {
      gam[nj] = gamma[nj * 16 + l15] * sc;
      bet[nj] = beta[nj * 16 + l15] * sc;
    }
#pragma unroll
    for (int mi = 0; mi < 4; ++mi) {
#pragma unroll
      for (int j = 0; j < 4; ++j) {
        float vals[4], s = 0.f, s2 = 0.f;
#pragma unroll
        for (int nj = 0; nj < 4; ++nj) {
          float v = acc[mi][nj][j] + biasv[nj];
          vals[nj] = v; s += v; s2 += v * v;
        }
        s = row16_sum(s);
        s2 = row16_sum(s2);
        const float mu = s * (1.0f / 64.0f);
        const float var = s2 * (1.0f / 64.0f) - mu * mu;
        const float rs = rsqrtf(var + 1e-5f);
        const int r = rowbase + mi * 16 + g * 4 + j;
        const int b = r >> 10, t = r & 1023;
        _Float16* drow = dst + ((size_t)((b * 16 + h) * 1024 + t)) * 64;
#pragma unroll
        for (int nj = 0; nj < 4; ++nj)
          drow[nj * 16 + l15] =
              (_Float16)((vals[nj] - mu) * rs * gam[nj] + bet[nj]);
      }
    }
  } else {
#pragma unroll
    for (int mi = 0; mi < 4; ++mi) {
      const int r0 = rowbase + mi * 16 + g * 4;
      const int b = r0 >> 10, t0 = r0 & 1023;
#pragma unroll
      for (int nj = 0; nj < 4; ++nj) {
        const int dk = nj * 16 + l15;
        half4v pk;
#pragma unroll
        for (int j = 0; j < 4; ++j)
          pk[j] = (_Float16)(acc[mi][nj][j] + biasv[nj]);
        *(half4v*)&VT[((size_t)((b * 16 + h) * 64 + dk)) * 1024 + t0] = pk;
      }
    }
  }
}

// ---------------------------------------------------------------- attention
// Grid (bh=64 on x, qt=8 on y): qt-blocks of one head share an XCD L2.
// Mask: mbits2 per-row u64 quads staged per 4-tile group (Mb2, dbuf).
#define PSTR 76

__global__ __launch_bounds__(512) void attn_kernel(
    const _Float16* __restrict__ Qln, const _Float16* __restrict__ Kln,
    const _Float16* __restrict__ VT,
    const unsigned long long* __restrict__ mbits, _Float16* __restrict__ X) {
  __shared__ _Float16 PQ[128 * PSTR];
  __shared__ _Float16 Ks[2][64 * 64];
  __shared__ _Float16 Vs[2][64 * 64];
  __shared__ unsigned long long Mb2[2][128 * 4];

  const int tid = threadIdx.x;
  const int w = tid >> 6, lane = tid & 63, g = lane >> 4, l15 = lane & 15;
  const int qt = blockIdx.y;  // 0..7
  const int bh = blockIdx.x;  // 0..63
  const int b = bh >> 4, h = bh & 15;

  const int lr8 = lane >> 3;
  const int csw = ((lane & 7) ^ lr8) << 3;

  const _Float16* Qb = Qln + (size_t)bh * 65536;
  const _Float16* Kb = Kln + (size_t)bh * 65536;
  const _Float16* Vb = VT + (size_t)bh * 65536;
  // mbits2: [row=b*1024+t][kgrp][c] u64 -> b's base = b*1024*16
  const unsigned long long* mbb = mbits + (size_t)b * 16384;

#define MB_STAGE(M, BUF)                                                     \
  if (w < 4)                                                                 \
    gload16(mbb + (size_t)(qt * 128 + w * 32 + (lane >> 1)) * 16 + (M)*4 +   \
                (lane & 1) * 2,                                              \
            &Mb2[BUF][(w * 32) * 4]);

  gload16(Qb + (size_t)(qt * 128 + w * 16 + lr8) * 64 + csw, &PQ[(w * 16) * 64]);
  gload16(Qb + (size_t)(qt * 128 + w * 16 + 8 + lr8) * 64 + csw,
          &PQ[(w * 16 + 8) * 64]);
  gload16(Kb + (size_t)(w * 8 + lr8) * 64 + csw, &Ks[0][(w * 8) * 64]);
  gload16(Vb + (size_t)(w * 8 + lr8) * 1024 + csw, &Vs[0][(w * 8) * 64]);
  MB_STAGE(0, 0)
  asm volatile("s_waitcnt vmcnt(0)" ::: "memory");
  __syncthreads();

  const int rsw = (l15 & 7) << 3;
  half8 qf[2];
#pragma unroll
  for (int kk = 0; kk < 2; ++kk)
    qf[kk] = *(const half8*)&PQ[(w * 16 + l15) * 64 + ((kk * 32 + g * 8) ^ rsw)];
  asm volatile("s_waitcnt lgkmcnt(0)" ::: "memory");
  __syncthreads();

  f32x4 o[4];
  float lsum[4];
#pragma unroll
  for (int dn = 0; dn < 4; ++dn) o[dn] = fzero4();
#pragma unroll
  for (int j = 0; j < 4; ++j) lsum[j] = 0.f;

#define ATTN_TILE(KT, CUR, NXT, PF)                                          \
  {                                                                          \
    if (PF) {                                                                \
      gload16(Kb + (size_t)(((KT) + 1) * 64 + w * 8 + lr8) * 64 + csw,       \
              &Ks[NXT][(w * 8) * 64]);                                       \
      gload16(Vb + (size_t)(w * 8 + lr8) * 1024 + ((KT) + 1) * 64 + csw,     \
              &Vs[NXT][(w * 8) * 64]);                                       \
    }                                                                        \
    if ((((KT) & 3) == 0) && (((KT) >> 2) < 3)) {                            \
      MB_STAGE(((KT) >> 2) + 1, (((KT) >> 2) + 1) & 1)                       \
    }                                                                        \
    f32x4 s[4];                                                              \
    _Pragma("unroll") for (int nj = 0; nj < 4; ++nj) s[nj] = fzero4();       \
    _Pragma("unroll") for (int kk = 0; kk < 2; ++kk) {                       \
      half8 qv = qf[kk];                                                     \
      __builtin_amdgcn_s_setprio(1);                                         \
      _Pragma("unroll") for (int nj = 0; nj < 4; ++nj) {                     \
        half8 kf = *(const half8*)&Ks[CUR][(nj * 16 + l15) * 64 +            \
                                          ((kk * 32 + g * 8) ^ rsw)];        \
        s[nj] = MFMA(qv, kf, s[nj]);                                         \
      }                                                                      \
      __builtin_amdgcn_s_setprio(0);                                         \
    }                                                                        \
    _Pragma("unroll") for (int j = 0; j < 4; ++j) {                          \
      const int lrow = w * 16 + g * 4 + j;                                   \
      const unsigned long long mw =                                          \
          Mb2[((KT) >> 2) & 1][lrow * 4 + (l15 & 3)];                        \
      const int bb = ((KT) & 3) * 16 + (l15 >> 2);                           \
      const float p0 = ((mw >> bb) & 1) ? 0.f : EXP2(s[0][j]);               \
      const float p1 = ((mw >> (bb + 4)) & 1) ? 0.f : EXP2(s[1][j]);         \
      const float p2 = ((mw >> (bb + 8)) & 1) ? 0.f : EXP2(s[2][j]);         \
      const float p3 = ((mw >> (bb + 12)) & 1) ? 0.f : EXP2(s[3][j]);        \
      PQ[lrow * PSTR + 0 + l15] = (_Float16)p0;                              \
      PQ[lrow * PSTR + 16 + l15] = (_Float16)p1;                             \
      PQ[lrow * PSTR + 32 + l15] = (_Float16)p2;                             \
      PQ[lrow * PSTR + 48 + l15] = (_Float16)p3;                             \
      lsum[j] += (p0 + p1) + (p2 + p3);                                      \
    }                                                                        \
    _Pragma("unroll") for (int kk = 0; kk < 2; ++kk) {                       \
      half8 pa = *(const half8*)&PQ[(w * 16 + l15) * PSTR + kk * 32 + g * 8];\
      __builtin_amdgcn_s_setprio(1);                                         \
      _Pragma("unroll") for (int dn = 0; dn < 4; ++dn) {                     \
        half8 vf = *(const half8*)&Vs[CUR][(dn * 16 + l15) * 64 +            \
                                           ((kk * 32 + g * 8) ^ rsw)];       \
        o[dn] = MFMA(pa, vf, o[dn]);                                         \
      }                                                                      \
      __builtin_amdgcn_s_setprio(0);                                         \
    }                                                                        \
    if (PF) {                                                                \
      asm volatile("s_waitcnt vmcnt(0)" ::: "memory");                       \
      __syncthreads();                                                       \
    }                                                                        \
  }

  for (int kt = 0; kt < 16; kt += 2) {
    ATTN_TILE(kt, 0, 1, true);
    ATTN_TILE(kt + 1, 1, 0, (kt + 1) < 15);
  }
#undef ATTN_TILE
#undef MB_STAGE

#pragma unroll
  for (int j = 0; j < 4; ++j) {
    const int t = qt * 128 + w * 16 + g * 4 + j;
    const float inv = 1.0f / row16_sum(lsum[j]);
    _Float16* xrow = X + ((size_t)(b * 1024 + t)) * 1024 + h * 64;
#pragma unroll
    for (int dn = 0; dn < 4; ++dn)
      xrow[dn * 16 + l15] = (_Float16)(o[dn][j] * inv);
  }
}

// ---------------------------------------------------------------- out proj
// 128x64 tiles (BK=64, 256 thr, 48 KB LDS dbuf): grid 512 -> 2 blocks/CU.
__global__ __launch_bounds__(256) void ogemm_kernel(
    const _Float16* __restrict__ Xin, const _Float16* __restrict__ Wo16,
    const float* __restrict__ bo, float* __restrict__ out) {
  __shared__ _Float16 As[2][128 * 64];
  __shared__ _Float16 Bs[2][64 * 64];

  const int tid = threadIdx.x;
  const int w = tid >> 6, lane = tid & 63, g = lane >> 4, l15 = lane & 15;
  const int flat = blockIdx.x;
  const int swz = (flat & 7) * 64 + (flat >> 3);  // XCD bijective (nwg=512)
  const int bn = swz & 15;   // 0..15 (64-col tiles)
  const int bm = swz >> 4;   // 0..31
  const int wr = w >> 1, wc = w & 1;
  const int srow = (w << 3) + (lane >> 3);
  const int lr8 = lane >> 3;
  const int csw = ((lane & 7) ^ lr8) << 3;
  const int rsw = (l15 & 7) << 3;

  f32x4 acc[4][2];
#pragma unroll
  for (int i = 0; i < 4; ++i)
#pragma unroll
    for (int j = 0; j < 2; ++j) acc[i][j] = fzero4();

#define OG_STAGE(KT, BUF)                                                   \
  {                                                                         \
    _Pragma("unroll") for (int r = 0; r < 4; ++r) {                         \
      gload16(Xin + (size_t)(bm * 128 + r * 32 + srow) * 1024 + (KT)*64 +   \
                  csw,                                                      \
              &As[BUF][(r * 32 + (w << 3)) * 64]);                          \
    }                                                                       \
    _Pragma("unroll") for (int c = 0; c < 2; ++c) {                         \
      gload16(Wo16 + (size_t)(bn * 64 + w * 16 + c * 8 + lr8) * 1024 +      \
                  (KT)*64 + csw,                                            \
              &Bs[BUF][(w * 16 + c * 8) * 64]);                             \
    }                                                                       \
  }

#define OG_TILE(KT, CUR, NXT, PF)                                           \
  {                                                                         \
    if (PF) { OG_STAGE((KT) + 1, NXT) }                                     \
    _Pragma("unroll") for (int kk = 0; kk < 2; ++kk) {                      \
      half8 a[4], b[2];                                                     \
      _Pragma("unroll") for (int mi = 0; mi < 4; ++mi) a[mi] =              \
          *(const half8*)&As[CUR][(wr * 64 + mi * 16 + l15) * 64 +          \
                                  ((kk * 32 + g * 8) ^ rsw)];               \
      _Pragma("unroll") for (int nj = 0; nj < 2; ++nj) b[nj] =              \
          *(const half8*)&Bs[CUR][(wc * 32 + nj * 16 + l15) * 64 +          \
                                  ((kk * 32 + g * 8) ^ rsw)];               \
      __builtin_amdgcn_s_setprio(1);                                        \
      _Pragma("unroll") for (int mi = 0; mi < 4; ++mi)                      \
          _Pragma("unroll") for (int nj = 0; nj < 2; ++nj) acc[mi][nj] =    \
              MFMA(a[mi], b[nj], acc[mi][nj]);                              \
      __builtin_amdgcn_s_setprio(0);                                        \
    }                                                                       \
    if (PF) {                                                               \
      asm volatile("s_waitcnt vmcnt(0)" ::: "memory");                      \
      __syncthreads();                                                      \
    }                                                                       \
  }

  OG_STAGE(0, 0)
  asm volatile("s_waitcnt vmcnt(0)" ::: "memory");
  __syncthreads();
  for (int kt = 0; kt < 16; kt += 2) {
    OG_TILE(kt, 0, 1, true);
    OG_TILE(kt + 1, 1, 0, (kt + 1) < 15);
  }
#undef OG_TILE
#undef OG_STAGE

  const int colbase = bn * 64 + wc * 32;
  const int rowbase = bm * 128 + wr * 64;
  float biasv[2];
#pragma unroll
  for (int nj = 0; nj < 2; ++nj) biasv[nj] = bo[colbase + nj * 16 + l15];
#pragma unroll
  for (int mi = 0; mi < 4; ++mi)
#pragma unroll
    for (int nj = 0; nj < 2; ++nj)
#pragma unroll
      for (int j = 0; j < 4; ++j) {
        const int r = rowbase + mi * 16 + g * 4 + j;
        out[(size_t)r * 1024 + colbase + nj * 16 + l15] =
            acc[mi][nj][j] + biasv[nj];
      }
}

// ---------------------------------------------------------------- launch
// Workspace layout (56.5 MB):
//   [0 .. 8MB)   q16 (phases 1-2), then X (phases 3-4; q16 dead)
//   [8 ..16MB)   k16   [16..24MB) v16   [24..32MB) w16
//   [32..40MB)   Qln   [40..48MB) Kln   [48..56MB) VTp
//   [56..56.5MB) mbits2
extern "C" void kernel_launch(void* const* d_in, const int* in_sizes, int n_in,
                              void* d_out, int out_size, void* d_ws,
                              size_t ws_size, hipStream_t stream) {
  const float* query = (const float*)d_in[0];
  const float* key = (const float*)d_in[1];
  const float* value = (const float*)d_in[2];
  const int* mask = (const int*)d_in[3];
  const float* Wq = (const float*)d_in[4];
  const float* bq = (const float*)d_in[5];
  const float* Wk = (const float*)d_in[6];
  const float* bk = (const float*)d_in[7];
  const float* Wv = (const float*)d_in[8];
  const float* bv = (const float*)d_in[9];
  const float* Wo = (const float*)d_in[10];
  const float* bo = (const float*)d_in[11];
  const float* qg = (const float*)d_in[12];
  const float* qb = (const float*)d_in[13];
  const float* kg = (const float*)d_in[14];
  const float* kb = (const float*)d_in[15];
  float* out = (float*)d_out;

  const size_t M4 = (size_t)4 * 1024 * 1024;
  const size_t M1 = (size_t)1024 * 1024;
  _Float16* q16 = (_Float16*)d_ws;
  _Float16* k16 = q16 + M4;
  _Float16* v16 = k16 + M4;
  _Float16* w16 = v16 + M4;
  _Float16* Qln = w16 + M4;
  _Float16* Kln = Qln + M4;
  _Float16* VTp = Kln + M4;
  _Float16* X = q16;  // aliases q16 — dead after proj, written by attn
  unsigned long long* mbits = (unsigned long long*)(VTp + M4);  // 56..56.5MB

  PrepArgs pa;
  pa.src[0] = query; pa.src[1] = key; pa.src[2] = value;
  pa.src[3] = Wq; pa.src[4] = Wk; pa.src[5] = Wv; pa.src[6] = Wo;
  pa.dst[0] = q16; pa.dst[1] = k16; pa.dst[2] = v16;
  pa.dst[3] = w16; pa.dst[4] = w16 + M1; pa.dst[5] = w16 + 2 * M1;
  pa.dst[6] = w16 + 3 * M1;
  pa.mask = mask;
  pa.mbits = mbits;

  prep_kernel<<<dim3(512, 8), 256, 0, stream>>>(pa);
  proj_kernel<<<dim3(768), 256, 0, stream>>>(
      q16, k16, v16, w16, bq, bk, bv, qg, qb, kg, kb, Qln, Kln, VTp);
  attn_kernel<<<dim3(64, 8), 512, 0, stream>>>(Qln, Kln, VTp, mbits, X);
  ogemm_kernel<<<dim3(512), 256, 0, stream>>>(X, w16 + 3 * M1, bo, out);
}

// Round 20
// 113.723 us; speedup vs baseline: 1.1964x; 1.0147x over previous
//
#include <hip/hip_runtime.h>
#include <cstdint>
#include <cstddef>

typedef _Float16 half8  __attribute__((ext_vector_type(8)));
typedef _Float16 half4v __attribute__((ext_vector_type(4)));
typedef float    f32x4  __attribute__((ext_vector_type(4)));

__device__ __forceinline__ f32x4 fzero4() {
  f32x4 v; v[0] = v[1] = v[2] = v[3] = 0.0f; return v;
}

__device__ __forceinline__ void gload16(const void* g, void* l) {
  __builtin_amdgcn_global_load_lds(
      (const __attribute__((address_space(1))) unsigned int*)g,
      (__attribute__((address_space(3))) unsigned int*)l, 16, 0, 0);
}

#define MFMA(a, b, c) __builtin_amdgcn_mfma_f32_16x16x32_f16(a, b, c, 0, 0, 0)
#define EXP2(x) __builtin_amdgcn_exp2f(x)

// 16-lane-row butterfly sum on the VALU pipe via DPP row_ror.
__device__ __forceinline__ float row16_sum(float x) {
#define STEP_(N)                                                         \
  {                                                                      \
    int t_ = __builtin_amdgcn_update_dpp(0, __float_as_int(x), 0x120 | N, \
                                         0xf, 0xf, true);                \
    x = x + __int_as_float(t_);                                          \
  }
  STEP_(8) STEP_(4) STEP_(2) STEP_(1)
#undef STEP_
  return x;
}

// ------------------------------------------- prep: weights cvt + mask bits
// mbits2 layout: [row=b*1024+t][kgrp(4)][c(4)] u64; bit l of (row,kg,c)
//   <-> mask[row][kg*256 + l*4 + c].
struct PrepArgs {
  const float* wsrc[4];
  _Float16*    wdst[4];
  const int*   mask;
  unsigned long long* mbits;
};

__global__ __launch_bounds__(256) void prep_kernel(PrepArgs a) {
  const int z = blockIdx.y;
  const int nthr = gridDim.x * blockDim.x;  // 131072
  const int t0 = blockIdx.x * blockDim.x + threadIdx.x;
  if (z < 4) {
    const float4* __restrict__ s = (const float4*)a.wsrc[z];
    half4v* __restrict__ d = (half4v*)a.wdst[z];
    float4 v[2];
#pragma unroll
    for (int k = 0; k < 2; ++k) v[k] = s[t0 + k * nthr];
#pragma unroll
    for (int k = 0; k < 2; ++k) {
      half4v h;
      h[0] = (_Float16)v[k].x; h[1] = (_Float16)v[k].y;
      h[2] = (_Float16)v[k].z; h[3] = (_Float16)v[k].w;
      d[t0 + k * nthr] = h;
    }
  } else {
    const int* __restrict__ src = a.mask;
    const unsigned char* __restrict__ s8 = (const unsigned char*)src;
    unsigned long long* __restrict__ dst = a.mbits;
    const int lane = threadIdx.x & 63;
    unsigned probe = 0;
#pragma unroll
    for (int e = 0; e < 16; ++e) probe |= s8[4 * (lane * 16 + e) + 1];
    const bool isbool = __any(probe != 0);

    const int wv = blockIdx.x * 4 + (threadIdx.x >> 6);  // 0..2047
    if (!isbool) {
      const int4* __restrict__ s4 = (const int4*)src;
      int4 mv[8];
#pragma unroll
      for (int i = 0; i < 8; ++i) {
        const int unit = wv * 8 + i;  // 0..16383
        const int row = unit >> 2, kg = unit & 3;
        mv[i] = s4[row * 256 + kg * 64 + lane];
      }
#pragma unroll
      for (int i = 0; i < 8; ++i) {
        const int unit = wv * 8 + i;
        unsigned long long w0 = __ballot(mv[i].x != 0);
        unsigned long long w1 = __ballot(mv[i].y != 0);
        unsigned long long w2 = __ballot(mv[i].z != 0);
        unsigned long long w3 = __ballot(mv[i].w != 0);
        if (lane == 0) {
          unsigned long long* p = dst + (size_t)unit * 4;
          p[0] = w0; p[1] = w1; p[2] = w2; p[3] = w3;
        }
      }
    } else {
      for (int i = 0; i < 8; ++i) {
        const int unit = wv * 8 + i;
        const int row = unit >> 2, kg = unit & 3;
#pragma unroll
        for (int c = 0; c < 4; ++c) {
          int m = s8[(size_t)row * 1024 + kg * 256 + lane * 4 + c];
          unsigned long long bw = __ballot(m != 0);
          if (lane == 0) dst[(size_t)unit * 4 + c] = bw;
        }
      }
    }
  }
}

// ---------------------------------------------------------------- projections
// m97-structure, SINGLE-buffered: A staged as FP32 via gload_lds (32 KB,
// parity-preserving 16B-slot swizzle: slot ^= (row&7)<<1), B fp16 (16 KB).
// 48 KB -> 3 blocks/CU. fp32->fp16 cvt on the READ side inside COMP.
#define SM_SCALE 0.18033688011112042f /* 0.125 * log2(e) */

__global__ __launch_bounds__(256) void proj_kernel(
    const float* __restrict__ query, const float* __restrict__ key,
    const float* __restrict__ value, const _Float16* __restrict__ w16,
    const float* __restrict__ bq, const float* __restrict__ bk,
    const float* __restrict__ bv,
    const float* __restrict__ qg, const float* __restrict__ qbt,
    const float* __restrict__ kg, const float* __restrict__ kbt,
    _Float16* __restrict__ Qln, _Float16* __restrict__ Kln,
    _Float16* __restrict__ VT) {
  __shared__ float    As[128 * 64];  // 32 KB fp32 A tile
  __shared__ _Float16 Bs[128 * 64];  // 16 KB fp16 B tile

  const int tid = threadIdx.x;
  const int w = tid >> 6, lane = tid & 63, g = lane >> 4, l15 = lane & 15;
  // XCD-aware bijective swizzle (nwg=768 -> q=96)
  const int flat = blockIdx.x;
  const int swz = (flat & 7) * 96 + (flat >> 3);
  const int bn = swz & 7;
  const int bm = (swz >> 3) & 31;
  const int z = swz >> 8;

  const float* Af = (z == 0) ? query : ((z == 1) ? key : value);
  const _Float16* W = w16 + (size_t)z * (1024 * 1024);
  const float* bias = (z == 0) ? bq : ((z == 1) ? bk : bv);

  const int wr = w >> 1, wc = w & 1;
  const int srow = (w << 3) + (lane >> 3);
  const int csw = ((lane & 7) ^ (lane >> 3)) << 3;  // B swizzled source col
  const int rsw = (l15 & 7) << 3;                   // B read-side XOR

  // A staging: call c stages rows c*16 + w*4 + (lane>>4); 16B slot lane&15;
  // source slot pre-swizzled by ((row&7)<<1).
  const int arowin = w * 4 + (lane >> 4);  // + c*16
  const int acsw = (((lane & 15) ^ ((arowin & 7) << 1)) << 2);  // fp32 col
  const int arsw = (l15 & 7) << 1;  // read-side slot XOR

  f32x4 acc[4][4];
#pragma unroll
  for (int i = 0; i < 4; ++i)
#pragma unroll
    for (int j = 0; j < 4; ++j) acc[i][j] = fzero4();

#define PROJ_STAGE(KT)                                                      \
  _Pragma("unroll") for (int c = 0; c < 8; ++c) {                           \
    gload16(Af + (size_t)(bm * 128 + c * 16 + arowin) * 1024 + (KT)*64 +    \
                acsw,                                                       \
            &As[(c * 16 + w * 4) * 64]);                                    \
  }                                                                         \
  _Pragma("unroll") for (int r = 0; r < 4; ++r) {                           \
    gload16(W + (size_t)(bn * 128 + r * 32 + srow) * 1024 + (KT)*64 + csw,  \
            &Bs[(r * 32 + (w << 3)) * 64]);                                 \
  }

#define PROJ_COMP()                                                         \
  _Pragma("unroll") for (int kk = 0; kk < 2; ++kk) {                        \
    half8 a[4], b[4];                                                       \
    _Pragma("unroll") for (int mi = 0; mi < 4; ++mi) {                      \
      const int arow = (wr * 64 + mi * 16 + l15) * 64;                      \
      const int s0 = (kk * 8 + g * 2) ^ arsw;                               \
      const int s1 = (kk * 8 + g * 2 + 1) ^ arsw;                           \
      f32x4 lo = *(const f32x4*)&As[arow + s0 * 4];                         \
      f32x4 hi = *(const f32x4*)&As[arow + s1 * 4];                         \
      half8 av;                                                             \
      av[0] = (_Float16)lo[0]; av[1] = (_Float16)lo[1];                     \
      av[2] = (_Float16)lo[2]; av[3] = (_Float16)lo[3];                     \
      av[4] = (_Float16)hi[0]; av[5] = (_Float16)hi[1];                     \
      av[6] = (_Float16)hi[2]; av[7] = (_Float16)hi[3];                     \
      a[mi] = av;                                                           \
    }                                                                       \
    _Pragma("unroll") for (int nj = 0; nj < 4; ++nj) b[nj] =                \
        *(const half8*)&Bs[(wc * 64 + nj * 16 + l15) * 64 +                 \
                           ((kk * 32 + g * 8) ^ rsw)];                      \
    __builtin_amdgcn_s_setprio(1);                                          \
    _Pragma("unroll") for (int mi = 0; mi < 4; ++mi)                        \
        _Pragma("unroll") for (int nj = 0; nj < 4; ++nj) acc[mi][nj] =      \
            MFMA(a[mi], b[nj], acc[mi][nj]);                                \
    __builtin_amdgcn_s_setprio(0);                                          \
  }

  for (int kt = 0; kt < 16; ++kt) {
    PROJ_STAGE(kt)
    asm volatile("s_waitcnt vmcnt(0)" ::: "memory");
    __syncthreads();
    PROJ_COMP()
    __syncthreads();
  }
#undef PROJ_COMP
#undef PROJ_STAGE

  const int colbase = bn * 128 + wc * 64;
  const int h = colbase >> 6;
  const int rowbase = bm * 128 + wr * 64;

  float biasv[4];
#pragma unroll
  for (int nj = 0; nj < 4; ++nj) biasv[nj] = bias[colbase + nj * 16 + l15];

  if (z < 2) {
    const float* gamma = (z == 0) ? qg : kg;
    const float* beta = (z == 0) ? qbt : kbt;
    const float sc = (z == 0) ? SM_SCALE : 1.0f;  // fold softmax scale into Q
    _Float16* dst = (z == 0) ? Qln : Kln;
    float gam[4], bet[4];
#pragma unroll
    for (int nj = 0; nj < 4; ++nj) {
      gam[nj] = gamma[nj * 16 + l15] * sc;
      bet[nj] = beta[nj * 16 + l15] * sc;
    }
#pragma unroll
    for (int mi = 0; mi < 4; ++mi) {
#pragma unroll
      for (int j = 0; j < 4; ++j) {
        float vals[4], s = 0.f, s2 = 0.f;
#pragma unroll
        for (int nj = 0; nj < 4; ++nj) {
          float v = acc[mi][nj][j] + biasv[nj];
          vals[nj] = v; s += v; s2 += v * v;
        }
        s = row16_sum(s);
        s2 = row16_sum(s2);
        const float mu = s * (1.0f / 64.0f);
        const float var = s2 * (1.0f / 64.0f) - mu * mu;
        const float rs = rsqrtf(var + 1e-5f);
        const int r = rowbase + mi * 16 + g * 4 + j;
        const int b = r >> 10, t = r & 1023;
        _Float16* drow = dst + ((size_t)((b * 16 + h) * 1024 + t)) * 64;
#pragma unroll
        for (int nj = 0; nj < 4; ++nj)
          drow[nj * 16 + l15] =
              (_Float16)((vals[nj] - mu) * rs * gam[nj] + bet[nj]);
      }
    }
  } else {
#pragma unroll
    for (int mi = 0; mi < 4; ++mi) {
      const int r0 = rowbase + mi * 16 + g * 4;
      const int b = r0 >> 10, t0 = r0 & 1023;
#pragma unroll
      for (int nj = 0; nj < 4; ++nj) {
        const int dk = nj * 16 + l15;
        half4v pk;
#pragma unroll
        for (int j = 0; j < 4; ++j)
          pk[j] = (_Float16)(acc[mi][nj][j] + biasv[nj]);
        *(half4v*)&VT[((size_t)((b * 16 + h) * 64 + dk)) * 1024 + t0] = pk;
      }
    }
  }
}

// ---------------------------------------------------------------- attention
// Grid (bh=64 on x, qt=8 on y): qt-blocks of one head share an XCD L2.
// Mask: mbits2 per-row u64 quads staged per 4-tile group (Mb2, dbuf).
#define PSTR 76

__global__ __launch_bounds__(512) void attn_kernel(
    const _Float16* __restrict__ Qln, const _Float16* __restrict__ Kln,
    const _Float16* __restrict__ VT,
    const unsigned long long* __restrict__ mbits, _Float16* __restrict__ X) {
  __shared__ _Float16 PQ[128 * PSTR];
  __shared__ _Float16 Ks[2][64 * 64];
  __shared__ _Float16 Vs[2][64 * 64];
  __shared__ unsigned long long Mb2[2][128 * 4];

  const int tid = threadIdx.x;
  const int w = tid >> 6, lane = tid & 63, g = lane >> 4, l15 = lane & 15;
  const int qt = blockIdx.y;  // 0..7
  const int bh = blockIdx.x;  // 0..63
  const int b = bh >> 4, h = bh & 15;

  const int lr8 = lane >> 3;
  const int csw = ((lane & 7) ^ lr8) << 3;

  const _Float16* Qb = Qln + (size_t)bh * 65536;
  const _Float16* Kb = Kln + (size_t)bh * 65536;
  const _Float16* Vb = VT + (size_t)bh * 65536;
  const unsigned long long* mbb = mbits + (size_t)b * 16384;

#define MB_STAGE(M, BUF)                                                     \
  if (w < 4)                                                                 \
    gload16(mbb + (size_t)(qt * 128 + w * 32 + (lane >> 1)) * 16 + (M)*4 +   \
                (lane & 1) * 2,                                              \
            &Mb2[BUF][(w * 32) * 4]);

  gload16(Qb + (size_t)(qt * 128 + w * 16 + lr8) * 64 + csw, &PQ[(w * 16) * 64]);
  gload16(Qb + (size_t)(qt * 128 + w * 16 + 8 + lr8) * 64 + csw,
          &PQ[(w * 16 + 8) * 64]);
  gload16(Kb + (size_t)(w * 8 + lr8) * 64 + csw, &Ks[0][(w * 8) * 64]);
  gload16(Vb + (size_t)(w * 8 + lr8) * 1024 + csw, &Vs[0][(w * 8) * 64]);
  MB_STAGE(0, 0)
  asm volatile("s_waitcnt vmcnt(0)" ::: "memory");
  __syncthreads();

  const int rsw = (l15 & 7) << 3;
  half8 qf[2];
#pragma unroll
  for (int kk = 0; kk < 2; ++kk)
    qf[kk] = *(const half8*)&PQ[(w * 16 + l15) * 64 + ((kk * 32 + g * 8) ^ rsw)];
  asm volatile("s_waitcnt lgkmcnt(0)" ::: "memory");
  __syncthreads();

  f32x4 o[4];
  float lsum[4];
#pragma unroll
  for (int dn = 0; dn < 4; ++dn) o[dn] = fzero4();
#pragma unroll
  for (int j = 0; j < 4; ++j) lsum[j] = 0.f;

#define ATTN_TILE(KT, CUR, NXT, PF)                                          \
  {                                                                          \
    if (PF) {                                                                \
      gload16(Kb + (size_t)(((KT) + 1) * 64 + w * 8 + lr8) * 64 + csw,       \
              &Ks[NXT][(w * 8) * 64]);                                       \
      gload16(Vb + (size_t)(w * 8 + lr8) * 1024 + ((KT) + 1) * 64 + csw,     \
              &Vs[NXT][(w * 8) * 64]);                                       \
    }                                                                        \
    if ((((KT) & 3) == 0) && (((KT) >> 2) < 3)) {                            \
      MB_STAGE(((KT) >> 2) + 1, (((KT) >> 2) + 1) & 1)                       \
    }                                                                        \
    f32x4 s[4];                                                              \
    _Pragma("unroll") for (int nj = 0; nj < 4; ++nj) s[nj] = fzero4();       \
    _Pragma("unroll") for (int kk = 0; kk < 2; ++kk) {                       \
      half8 qv = qf[kk];                                                     \
      __builtin_amdgcn_s_setprio(1);                                         \
      _Pragma("unroll") for (int nj = 0; nj < 4; ++nj) {                     \
        half8 kf = *(const half8*)&Ks[CUR][(nj * 16 + l15) * 64 +            \
                                          ((kk * 32 + g * 8) ^ rsw)];        \
        s[nj] = MFMA(qv, kf, s[nj]);                                         \
      }                                                                      \
      __builtin_amdgcn_s_setprio(0);                                         \
    }                                                                        \
    _Pragma("unroll") for (int j = 0; j < 4; ++j) {                          \
      const int lrow = w * 16 + g * 4 + j;                                   \
      const unsigned long long mw =                                          \
          Mb2[((KT) >> 2) & 1][lrow * 4 + (l15 & 3)];                        \
      const int bb = ((KT) & 3) * 16 + (l15 >> 2);                           \
      const float p0 = ((mw >> bb) & 1) ? 0.f : EXP2(s[0][j]);               \
      const float p1 = ((mw >> (bb + 4)) & 1) ? 0.f : EXP2(s[1][j]);         \
      const float p2 = ((mw >> (bb + 8)) & 1) ? 0.f : EXP2(s[2][j]);         \
      const float p3 = ((mw >> (bb + 12)) & 1) ? 0.f : EXP2(s[3][j]);        \
      PQ[lrow * PSTR + 0 + l15] = (_Float16)p0;                              \
      PQ[lrow * PSTR + 16 + l15] = (_Float16)p1;                             \
      PQ[lrow * PSTR + 32 + l15] = (_Float16)p2;                             \
      PQ[lrow * PSTR + 48 + l15] = (_Float16)p3;                             \
      lsum[j] += (p0 + p1) + (p2 + p3);                                      \
    }                                                                        \
    _Pragma("unroll") for (int kk = 0; kk < 2; ++kk) {                       \
      half8 pa = *(const half8*)&PQ[(w * 16 + l15) * PSTR + kk * 32 + g * 8];\
      __builtin_amdgcn_s_setprio(1);                                         \
      _Pragma("unroll") for (int dn = 0; dn < 4; ++dn) {                     \
        half8 vf = *(const half8*)&Vs[CUR][(dn * 16 + l15) * 64 +            \
                                           ((kk * 32 + g * 8) ^ rsw)];       \
        o[dn] = MFMA(pa, vf, o[dn]);                                         \
      }                                                                      \
      __builtin_amdgcn_s_setprio(0);                                         \
    }                                                                        \
    if (PF) {                                                                \
      asm volatile("s_waitcnt vmcnt(0)" ::: "memory");                       \
      __syncthreads();                                                       \
    }                                                                        \
  }

  for (int kt = 0; kt < 16; kt += 2) {
    ATTN_TILE(kt, 0, 1, true);
    ATTN_TILE(kt + 1, 1, 0, (kt + 1) < 15);
  }
#undef ATTN_TILE
#undef MB_STAGE

#pragma unroll
  for (int j = 0; j < 4; ++j) {
    const int t = qt * 128 + w * 16 + g * 4 + j;
    const float inv = 1.0f / row16_sum(lsum[j]);
    _Float16* xrow = X + ((size_t)(b * 1024 + t)) * 1024 + h * 64;
#pragma unroll
    for (int dn = 0; dn < 4; ++dn)
      xrow[dn * 16 + l15] = (_Float16)(o[dn][j] * inv);
  }
}

// ---------------------------------------------------------------- out proj
// 128x64 tiles (BK=64, 256 thr, 48 KB LDS dbuf): grid 512 -> 2 blocks/CU.
__global__ __launch_bounds__(256) void ogemm_kernel(
    const _Float16* __restrict__ Xin, const _Float16* __restrict__ Wo16,
    const float* __restrict__ bo, float* __restrict__ out) {
  __shared__ _Float16 As[2][128 * 64];
  __shared__ _Float16 Bs[2][64 * 64];

  const int tid = threadIdx.x;
  const int w = tid >> 6, lane = tid & 63, g = lane >> 4, l15 = lane & 15;
  const int flat = blockIdx.x;
  const int swz = (flat & 7) * 64 + (flat >> 3);  // XCD bijective (nwg=512)
  const int bn = swz & 15;   // 0..15 (64-col tiles)
  const int bm = swz >> 4;   // 0..31
  const int wr = w >> 1, wc = w & 1;
  const int srow = (w << 3) + (lane >> 3);
  const int lr8 = lane >> 3;
  const int csw = ((lane & 7) ^ lr8) << 3;
  const int rsw = (l15 & 7) << 3;

  f32x4 acc[4][2];
#pragma unroll
  for (int i = 0; i < 4; ++i)
#pragma unroll
    for (int j = 0; j < 2; ++j) acc[i][j] = fzero4();

#define OG_STAGE(KT, BUF)                                                   \
  {                                                                         \
    _Pragma("unroll") for (int r = 0; r < 4; ++r) {                         \
      gload16(Xin + (size_t)(bm * 128 + r * 32 + srow) * 1024 + (KT)*64 +   \
                  csw,                                                      \
              &As[BUF][(r * 32 + (w << 3)) * 64]);                          \
    }                                                                       \
    _Pragma("unroll") for (int c = 0; c < 2; ++c) {                         \
      gload16(Wo16 + (size_t)(bn * 64 + w * 16 + c * 8 + lr8) * 1024 +      \
                  (KT)*64 + csw,                                            \
              &Bs[BUF][(w * 16 + c * 8) * 64]);                             \
    }                                                                       \
  }

#define OG_TILE(KT, CUR, NXT, PF)                                           \
  {                                                                         \
    if (PF) { OG_STAGE((KT) + 1, NXT) }                                     \
    _Pragma("unroll") for (int kk = 0; kk < 2; ++kk) {                      \
      half8 a[4], b[2];                                                     \
      _Pragma("unroll") for (int mi = 0; mi < 4; ++mi) a[mi] =              \
          *(const half8*)&As[CUR][(wr * 64 + mi * 16 + l15) * 64 +          \
                                  ((kk * 32 + g * 8) ^ rsw)];               \
      _Pragma("unroll") for (int nj = 0; nj < 2; ++nj) b[nj] =              \
          *(const half8*)&Bs[CUR][(wc * 32 + nj * 16 + l15) * 64 +          \
                                  ((kk * 32 + g * 8) ^ rsw)];               \
      __builtin_amdgcn_s_setprio(1);                                        \
      _Pragma("unroll") for (int mi = 0; mi < 4; ++mi)                      \
          _Pragma("unroll") for (int nj = 0; nj < 2; ++nj) acc[mi][nj] =    \
              MFMA(a[mi], b[nj], acc[mi][nj]);                              \
      __builtin_amdgcn_s_setprio(0);                                        \
    }                                                                       \
    if (PF) {                                                               \
      asm volatile("s_waitcnt vmcnt(0)" ::: "memory");                      \
      __syncthreads();                                                      \
    }                                                                       \
  }

  OG_STAGE(0, 0)
  asm volatile("s_waitcnt vmcnt(0)" ::: "memory");
  __syncthreads();
  for (int kt = 0; kt < 16; kt += 2) {
    OG_TILE(kt, 0, 1, true);
    OG_TILE(kt + 1, 1, 0, (kt + 1) < 15);
  }
#undef OG_TILE
#undef OG_STAGE

  const int colbase = bn * 64 + wc * 32;
  const int rowbase = bm * 128 + wr * 64;
  float biasv[2];
#pragma unroll
  for (int nj = 0; nj < 2; ++nj) biasv[nj] = bo[colbase + nj * 16 + l15];
#pragma unroll
  for (int mi = 0; mi < 4; ++mi)
#pragma unroll
    for (int nj = 0; nj < 2; ++nj)
#pragma unroll
      for (int j = 0; j < 4; ++j) {
        const int r = rowbase + mi * 16 + g * 4 + j;
        out[(size_t)r * 1024 + colbase + nj * 16 + l15] =
            acc[mi][nj][j] + biasv[nj];
      }
}

// ---------------------------------------------------------------- launch
// Workspace layout (56.5 MB):
//   [0 .. 8MB)   X (written by attn, read by ogemm)
//   [24..32MB)   w16 (Wq,Wk,Wv,Wo fp16)
//   [32..40MB)   Qln   [40..48MB) Kln   [48..56MB) VTp
//   [56..56.5MB) mbits2
extern "C" void kernel_launch(void* const* d_in, const int* in_sizes, int n_in,
                              void* d_out, int out_size, void* d_ws,
                              size_t ws_size, hipStream_t stream) {
  const float* query = (const float*)d_in[0];
  const float* key = (const float*)d_in[1];
  const float* value = (const float*)d_in[2];
  const int* mask = (const int*)d_in[3];
  const float* Wq = (const float*)d_in[4];
  const float* bq = (const float*)d_in[5];
  const float* Wk = (const float*)d_in[6];
  const float* bk = (const float*)d_in[7];
  const float* Wv = (const float*)d_in[8];
  const float* bv = (const float*)d_in[9];
  const float* Wo = (const float*)d_in[10];
  const float* bo = (const float*)d_in[11];
  const float* qg = (const float*)d_in[12];
  const float* qb = (const float*)d_in[13];
  const float* kg = (const float*)d_in[14];
  const float* kb = (const float*)d_in[15];
  float* out = (float*)d_out;

  const size_t M4 = (size_t)4 * 1024 * 1024;
  const size_t M1 = (size_t)1024 * 1024;
  _Float16* base = (_Float16*)d_ws;
  _Float16* X = base;                // [0..8MB)
  _Float16* w16 = base + 3 * M4;     // [24..32MB)
  _Float16* Qln = base + 4 * M4;     // [32..40MB)
  _Float16* Kln = base + 5 * M4;     // [40..48MB)
  _Float16* VTp = base + 6 * M4;     // [48..56MB)
  unsigned long long* mbits = (unsigned long long*)(base + 7 * M4);

  PrepArgs pa;
  pa.wsrc[0] = Wq; pa.wsrc[1] = Wk; pa.wsrc[2] = Wv; pa.wsrc[3] = Wo;
  pa.wdst[0] = w16; pa.wdst[1] = w16 + M1; pa.wdst[2] = w16 + 2 * M1;
  pa.wdst[3] = w16 + 3 * M1;
  pa.mask = mask;
  pa.mbits = mbits;

  prep_kernel<<<dim3(512, 5), 256, 0, stream>>>(pa);
  proj_kernel<<<dim3(768), 256, 0, stream>>>(
      query, key, value, w16, bq, bk, bv, qg, qb, kg, kb, Qln, Kln, VTp);
  attn_kernel<<<dim3(64, 8), 512, 0, stream>>>(Qln, Kln, VTp, mbits, X);
  ogemm_kernel<<<dim3(512), 256, 0, stream>>>(X, w16 + 3 * M1, bo, out);
}